// Round 12
// baseline (712.138 us; speedup 1.0000x reference)
//
#include <hip/hip_runtime.h>
#include <cmath>
#include <stdint.h>

#define NLEV  16
#define TSIZE (1u<<19)
#define PRES  512
#define PFD   8
#define HID   64
#define LDSH  72   // short stride per point row in MFMA LDS

struct ResArr { float v[NLEV]; };

typedef __attribute__((ext_vector_type(8))) short short8v;   // 8 bf16 (4 VGPRs)
typedef __attribute__((ext_vector_type(4))) float f32x4;

__device__ __forceinline__ float4 ld4(const float* p){ return *reinterpret_cast<const float4*>(p); }

__device__ __forceinline__ uint16_t f2bf(float f){
    uint32_t u = __float_as_uint(f);
    uint32_t r = (u + 0x7FFFu + ((u>>16)&1u)) >> 16;
    return (uint16_t)r;
}
__device__ __forceinline__ float bf2f(uint32_t h){ return __uint_as_float(h<<16); }

#define AXPY64(A, WPTR, V) do { const float* _w=(WPTR); const float _v=(V); \
  _Pragma("unroll") \
  for (int _o=0;_o<64;_o+=4){ float4 _w4=ld4(_w+_o); \
    A[_o+0]=fmaf(_w4.x,_v,A[_o+0]); A[_o+1]=fmaf(_w4.y,_v,A[_o+1]); \
    A[_o+2]=fmaf(_w4.z,_v,A[_o+2]); A[_o+3]=fmaf(_w4.w,_v,A[_o+3]); } } while(0)

__device__ __forceinline__ void plane_enc(const float* __restrict__ planes,
                                          float p0, float p1, float p2, float* pfv)
{
#pragma unroll
    for (int i=0;i<3;i++){
        float ua = (i==2? p1 : p0)*511.f;
        float va = (i==0? p1 : p2)*511.f;
        float uf=floorf(ua), vf=floorf(va);
        float wu=ua-uf, wv=va-vf;
        int u0=(int)uf; u0 = u0<0?0:(u0>510?510:u0);
        int v0=(int)vf; v0 = v0<0?0:(v0>510?510:v0);
        const float* pl = planes + ((size_t)i*PRES*PRES + (size_t)(u0*PRES+v0))*PFD;
        float4 a0=ld4(pl),              a1=ld4(pl+4);
        float4 b0=ld4(pl+PFD),          b1=ld4(pl+PFD+4);
        float4 c0=ld4(pl+PRES*PFD),     c1=ld4(pl+PRES*PFD+4);
        float4 d0=ld4(pl+PRES*PFD+PFD), d1=ld4(pl+PRES*PFD+PFD+4);
        float w00=(1.f-wu)*(1.f-wv), w01=(1.f-wu)*wv, w10=wu*(1.f-wv), w11=wu*wv;
        pfv[i*8+0]=a0.x*w00+b0.x*w01+c0.x*w10+d0.x*w11;
        pfv[i*8+1]=a0.y*w00+b0.y*w01+c0.y*w10+d0.y*w11;
        pfv[i*8+2]=a0.z*w00+b0.z*w01+c0.z*w10+d0.z*w11;
        pfv[i*8+3]=a0.w*w00+b0.w*w01+c0.w*w10+d0.w*w11;
        pfv[i*8+4]=a1.x*w00+b1.x*w01+c1.x*w10+d1.x*w11;
        pfv[i*8+5]=a1.y*w00+b1.y*w01+c1.y*w10+d1.y*w11;
        pfv[i*8+6]=a1.z*w00+b1.z*w01+c1.z*w10+d1.z*w11;
        pfv[i*8+7]=a1.w*w00+b1.w*w01+c1.w*w10+d1.w*w11;
    }
}

// ===================== krepack: hash tables -> bf16-packed u32 =====================
__global__ void nerf_krepack(const float2* __restrict__ tabs,
                             uint32_t* __restrict__ tabs_bf, int total)
{
    int i = blockIdx.x*256 + threadIdx.x;
    if (i < total){
        float2 t = tabs[i];
        tabs_bf[i] = (uint32_t)f2bf(t.x) | ((uint32_t)f2bf(t.y)<<16);
    }
}

// ===================== kprep: pack (pos01, app) into float4 =====================
__global__ void nerf_kprep(const float* __restrict__ x, float4* __restrict__ pp, int npts)
{
    int n = blockIdx.x*256 + threadIdx.x;
    if (n < npts){
        const float* xr = x + (size_t)n*7;
        pp[n] = make_float4((xr[0]+1.f)*0.5f, (xr[1]+1.f)*0.5f, (xr[2]+1.f)*0.5f, xr[6]);
    }
}

// ===================== K0b: level-major hash gather, bf16 tables, 4 pts/thread ====
__global__ __launch_bounds__(256, 2)
void nerf_k0b(const float4* __restrict__ pp,
              const uint32_t* __restrict__ tabs_bf,
              uint32_t* __restrict__ feat,
              ResArr res, int npts, int lvl_base)
{
    int bid   = blockIdx.x;
    int level = lvl_base + (bid & 7);
    int chunk = bid >> 3;
    int base_n = chunk*1024 + threadIdx.x;
    float R = res.v[level];
    const uint32_t* tab = tabs_bf + (size_t)level*TSIZE;

    uint32_t g[4][8];
    float rx[4], ry[4], rz[4];
    bool ok[4];
#pragma unroll
    for (int q=0;q<4;q++){
        int n = base_n + q*256;
        ok[q] = (n < npts);
        int nc = ok[q] ? n : 0;
        float4 p = pp[nc];
        float ax=p.x*R, ay=p.y*R, az=p.z*R;
        float fx=floorf(ax), fy=floorf(ay), fz=floorf(az);
        rx[q]=ax-fx; ry[q]=ay-fy; rz[q]=az-fz;
        uint32_t ix=(uint32_t)fx, iy=(uint32_t)fy, iz=(uint32_t)fz;
        uint32_t hx0=ix,             hx1=ix+1u;
        uint32_t hy0=iy*2654435761u, hy1=(iy+1u)*2654435761u;
        uint32_t hz0=iz*805459861u,  hz1=(iz+1u)*805459861u;
#pragma unroll
        for (int c=0;c<8;c++){
            uint32_t idx = (((c&4)?hx1:hx0) ^ ((c&2)?hy1:hy0) ^ ((c&1)?hz1:hz0)) & (TSIZE-1u);
            g[q][c] = tab[idx];
        }
    }
#pragma unroll
    for (int q=0;q<4;q++){
        float wx0=1.f-rx[q], wy0=1.f-ry[q], wz0=1.f-rz[q];
        float f0=0.f, f1=0.f;
#pragma unroll
        for (int c=0;c<8;c++){
            float w = ((c&4)?rx[q]:wx0)*((c&2)?ry[q]:wy0)*((c&1)?rz[q]:wz0);
            f0 = fmaf(w, bf2f(g[q][c] & 0xFFFFu), f0);
            f1 = fmaf(w, bf2f(g[q][c] >> 16),     f1);
        }
        int n = base_n + q*256;
        if (ok[q]) feat[(size_t)level*npts + n] = (uint32_t)f2bf(f0) | ((uint32_t)f2bf(f1)<<16);
    }
}

// ===================== K0: mid path (fp32 tables) =====================
__global__ __launch_bounds__(256, 2)
void nerf_k0(const float* __restrict__ x,
             const float* __restrict__ hash_tables,
             uint32_t* __restrict__ feat,
             ResArr res, int npts, int lvl_base)
{
    int bid   = blockIdx.x;
    int level = lvl_base + (bid & 7);
    int chunk = bid >> 3;
    int n0 = chunk*512 + threadIdx.x;
    int n1 = n0 + 256;
    float R = res.v[level];
    const float2* tab = reinterpret_cast<const float2*>(hash_tables) + (size_t)level*TSIZE;

    bool v0ok = (n0 < npts), v1ok = (n1 < npts);

    float p0a=0,p1a=0,p2a=0, p0b=0,p1b=0,p2b=0;
    if (v0ok){ const float* xr = x + (size_t)n0*7;
        p0a=(xr[0]+1.f)*0.5f; p1a=(xr[1]+1.f)*0.5f; p2a=(xr[2]+1.f)*0.5f; }
    if (v1ok){ const float* xr = x + (size_t)n1*7;
        p0b=(xr[0]+1.f)*0.5f; p1b=(xr[1]+1.f)*0.5f; p2b=(xr[2]+1.f)*0.5f; }

    float axa=p0a*R, aya=p1a*R, aza=p2a*R;
    float fxa=floorf(axa), fya=floorf(aya), fza=floorf(aza);
    float rxa=axa-fxa, rya=aya-fya, rza=aza-fza;
    uint32_t ixa=(uint32_t)fxa, iya=(uint32_t)fya, iza=(uint32_t)fza;
    uint32_t hx0a=ixa,             hx1a=ixa+1u;
    uint32_t hy0a=iya*2654435761u, hy1a=(iya+1u)*2654435761u;
    uint32_t hz0a=iza*805459861u,  hz1a=(iza+1u)*805459861u;

    float axb=p0b*R, ayb=p1b*R, azb=p2b*R;
    float fxb=floorf(axb), fyb=floorf(ayb), fzb=floorf(azb);
    float rxb=axb-fxb, ryb=ayb-fyb, rzb=azb-fzb;
    uint32_t ixb=(uint32_t)fxb, iyb=(uint32_t)fyb, izb=(uint32_t)fzb;
    uint32_t hx0b=ixb,             hx1b=ixb+1u;
    uint32_t hy0b=iyb*2654435761u, hy1b=(iyb+1u)*2654435761u;
    uint32_t hz0b=izb*805459861u,  hz1b=(izb+1u)*805459861u;

    float2 ta[8], tb[8];
#pragma unroll
    for (int c=0;c<8;c++){
        uint32_t idx = (((c&4)?hx1a:hx0a) ^ ((c&2)?hy1a:hy0a) ^ ((c&1)?hz1a:hz0a)) & (TSIZE-1u);
        ta[c] = tab[idx];
    }
#pragma unroll
    for (int c=0;c<8;c++){
        uint32_t idx = (((c&4)?hx1b:hx0b) ^ ((c&2)?hy1b:hy0b) ^ ((c&1)?hz1b:hz0b)) & (TSIZE-1u);
        tb[c] = tab[idx];
    }

    float wxa0=1.f-rxa, wya0=1.f-rya, wza0=1.f-rza;
    float f0a=0.f, f1a=0.f;
#pragma unroll
    for (int c=0;c<8;c++){
        float w = ((c&4)?rxa:wxa0)*((c&2)?rya:wya0)*((c&1)?rza:wza0);
        f0a = fmaf(w,ta[c].x,f0a); f1a = fmaf(w,ta[c].y,f1a);
    }
    float wxb0=1.f-rxb, wyb0=1.f-ryb, wzb0=1.f-rzb;
    float f0b=0.f, f1b=0.f;
#pragma unroll
    for (int c=0;c<8;c++){
        float w = ((c&4)?rxb:wxb0)*((c&2)?ryb:wyb0)*((c&1)?rzb:wzb0);
        f0b = fmaf(w,tb[c].x,f0b); f1b = fmaf(w,tb[c].y,f1b);
    }

    size_t base = (size_t)level*npts;
    if (v0ok) feat[base+n0] = (uint32_t)f2bf(f0a) | ((uint32_t)f2bf(f1a)<<16);
    if (v1ok) feat[base+n1] = (uint32_t)f2bf(f0b) | ((uint32_t)f2bf(f1b)<<16);
}

// ===================== ktrans: weight prep =====================
// B-fragment layout: idx = nt*1024 + ks*512 + l*8 + i
//   value = w[out = nt*16+(l&15)][k = ks*32+(l>>4)*8+i]
__global__ void nerf_ktrans(const float* __restrict__ w_sigma0,
                            const float* __restrict__ w_sigma1,
                            const float* __restrict__ w_color0,
                            const float* __restrict__ w_color1,
                            const float* __restrict__ w_color2,
                            float* __restrict__ t_s0, float* __restrict__ t_s1,
                            float* __restrict__ t_c2,
                            short* __restrict__ c0Bhi, short* __restrict__ c0Blo,
                            short* __restrict__ c1Bhi, short* __restrict__ c1Blo,
                            short* __restrict__ s0Bhi, short* __restrict__ s0Blo,
                            short* __restrict__ s1Bhi, short* __restrict__ s1Blo,
                            short* __restrict__ c2Bhi, short* __restrict__ c2Blo)
{
    int tid = threadIdx.x;
    for (int i=tid;i<56*64; i+=256){ int k=i>>6,o=i&63; t_s0[i]=w_sigma0[o*56+k]; }
    for (int i=tid;i<64*16; i+=256){ int k=i>>4,j=i&15; t_s1[i]=w_sigma1[j*64+k]; }
    for (int i=tid;i<64*4;  i+=256){ int k=i>>2,o=i&3;  t_c2[i]=(o<3)?w_color2[o*64+k]:0.f; }

    for (int idx=tid; idx<4096; idx+=256){
        int nt = idx >> 10;
        int r1 = idx & 1023;
        int ks = r1 >> 9;
        int r2 = r1 & 511;
        int l  = r2 >> 3;
        int i  = r2 & 7;
        int out = nt*16 + (l & 15);
        int kk  = ks*32 + (l >> 4)*8 + i;
        float w0 = 0.f;
        if (kk < 31)       w0 = w_color0[out*103 + kk];
        else if (kk < 55)  w0 = w_color0[out*103 + kk + 48];
        uint16_t h0 = f2bf(w0);
        uint16_t l0 = f2bf(w0 - bf2f(h0));
        c0Bhi[idx] = (short)h0; c0Blo[idx] = (short)l0;
        float w1 = w_color1[out*64 + kk];
        uint16_t h1 = f2bf(w1);
        uint16_t l1 = f2bf(w1 - bf2f(h1));
        c1Bhi[idx] = (short)h1; c1Blo[idx] = (short)l1;
        float ws = (kk < 56) ? w_sigma0[out*56 + kk] : 0.f;
        uint16_t hs = f2bf(ws);
        uint16_t ls = f2bf(ws - bf2f(hs));
        s0Bhi[idx] = (short)hs; s0Blo[idx] = (short)ls;
    }
    // sigma1 (out=16) and color2 (out=3): 1 nt tile, idx = ks*512 + l*8 + i
    for (int idx=tid; idx<1024; idx+=256){
        int ks = idx >> 9;
        int r2 = idx & 511;
        int l  = r2 >> 3;
        int i  = r2 & 7;
        int out = l & 15;
        int kk  = ks*32 + (l >> 4)*8 + i;
        float w = w_sigma1[out*64 + kk];
        uint16_t h = f2bf(w);
        s1Bhi[idx] = (short)h; s1Blo[idx] = (short)f2bf(w - bf2f(h));
        float wc = (out < 3) ? w_color2[out*64 + kk] : 0.f;
        uint16_t hc2 = f2bf(wc);
        c2Bhi[idx] = (short)hc2; c2Blo[idx] = (short)f2bf(wc - bf2f(hc2));
    }
}

// ===================== kpre: app_pre[a][o] =====================
__global__ void nerf_kpre(const float* __restrict__ embed_a,
                          const float* __restrict__ w_color0,
                          float* __restrict__ app_pre)
{
    int a = blockIdx.x;
    int o = threadIdx.x;   // 64
    const float* er = embed_a + (size_t)a*48;
    const float* wr = w_color0 + (size_t)o*103 + 31;
    float s = 0.f;
#pragma unroll
    for (int j=0;j<48;j++) s = fmaf(er[j], wr[j], s);
    app_pre[(size_t)a*64 + o] = s;
}

// ===================== K1s: mid-path sigma MLP (VALU) =====================
__global__ __launch_bounds__(256, 2)
void nerf_k1s(const float* __restrict__ x,
              const float* __restrict__ planes,
              uint32_t* __restrict__ feat,
              const float* __restrict__ wT_s0,
              const float* __restrict__ wT_s1,
              int npts)
{
    int n = blockIdx.x*256 + threadIdx.x;
    if (n >= npts) return;

    uint32_t fl[NLEV];
#pragma unroll
    for (int l=0;l<NLEV;l++) fl[l] = feat[(size_t)l*npts + n];

    float acc[HID];
#pragma unroll
    for (int o=0;o<HID;o++) acc[o]=0.f;

#pragma unroll
    for (int l=0;l<NLEV;l++){
        float f0 = bf2f(fl[l] & 0xFFFFu);
        float f1 = bf2f(fl[l] >> 16);
        AXPY64(acc, &wT_s0[(2*l+0)*64], f0);
        AXPY64(acc, &wT_s0[(2*l+1)*64], f1);
    }

    const float* xr = x + (size_t)n*7;
    float p0=(xr[0]+1.f)*0.5f, p1=(xr[1]+1.f)*0.5f, p2=(xr[2]+1.f)*0.5f;
    float pfv[24];
    plane_enc(planes, p0, p1, p2, pfv);
#pragma unroll
    for (int j=0;j<24;j++){
        AXPY64(acc, &wT_s0[(32+j)*64], pfv[j]);
    }

    float h1[16];
#pragma unroll
    for (int j=0;j<16;j++) h1[j]=0.f;
#pragma unroll
    for (int k=0;k<HID;k++){
        float v = fmaxf(acc[k], 0.f);
        const float* wr = &wT_s1[k*16];
#pragma unroll
        for (int j=0;j<16;j+=4){
            float4 w=ld4(wr+j);
            h1[j+0]=fmaf(w.x,v,h1[j+0]); h1[j+1]=fmaf(w.y,v,h1[j+1]);
            h1[j+2]=fmaf(w.z,v,h1[j+2]); h1[j+3]=fmaf(w.w,v,h1[j+3]);
        }
    }
    float sg = fminf(fmaxf(h1[0], -15.f), 15.f);
    float sigma = expf(sg);

#pragma unroll
    for (int l=0;l<15;l++) feat[(size_t)l*npts + n] = __float_as_uint(h1[l+1]);
    feat[(size_t)15*npts + n] = __float_as_uint(sigma);
}

// ===================== K2m: mid-path color MLP (MFMA, R8-verified) =====================
__global__ __launch_bounds__(64, 1)
void nerf_k2m(const float* __restrict__ x,
              const float* __restrict__ planes,
              const uint32_t* __restrict__ feat,
              const float* __restrict__ app_pre,
              const short* __restrict__ c0Bhi, const short* __restrict__ c0Blo,
              const short* __restrict__ c1Bhi, const short* __restrict__ c1Blo,
              const float* __restrict__ t_c2,
              float* __restrict__ out, int npts)
{
    __shared__ uint16_t ldsA[2*64*LDSH];
    __shared__ int      lds_ai[64];

    const int l = threadIdx.x;
    int n = blockIdx.x*64 + l;
    bool ok = (n < npts);
    int nc = ok ? n : (npts-1);
    const float* xr = x + (size_t)nc*7;

    {
        float av[55];
        float dx=xr[3], dy=xr[4], dz=xr[5];
        float nrm = sqrtf(dx*dx+dy*dy+dz*dz);
        float sx=dx/nrm, sy=dy/nrm, sz=dz/nrm;
        float xx=sx*sx, yy=sy*sy, zz=sz*sz, xyv=sx*sy, yzv=sy*sz, xzv=sx*sz;
        av[0]=0.28209479177387814f;
        av[1]=-0.48860251190291987f*sy;
        av[2]= 0.48860251190291987f*sz;
        av[3]=-0.48860251190291987f*sx;
        av[4]= 1.0925484305920792f*xyv;
        av[5]=-1.0925484305920792f*yzv;
        av[6]= 0.94617469575756f*zz-0.31539156525252005f;
        av[7]=-1.0925484305920792f*xzv;
        av[8]= 0.5462742152960396f*(xx-yy);
        av[9]=-0.5900435899266435f*sy*(3.f*xx-yy);
        av[10]=2.890611442640554f*xyv*sz;
        av[11]=-0.4570457994644658f*sy*(4.f*zz-xx-yy);
        av[12]=0.3731763325901154f*sz*(2.f*zz-3.f*xx-3.f*yy);
        av[13]=-0.4570457994644658f*sx*(4.f*zz-xx-yy);
        av[14]=1.445305721320277f*sz*(xx-yy);
        av[15]=-0.5900435899266435f*sx*(xx-3.f*yy);
#pragma unroll
        for (int j=0;j<15;j++) av[16+j] = __uint_as_float(feat[(size_t)j*npts + nc]);
        float pfv[24];
        plane_enc(planes, (xr[0]+1.f)*0.5f, (xr[1]+1.f)*0.5f, (xr[2]+1.f)*0.5f, pfv);
#pragma unroll
        for (int j=0;j<24;j++) av[31+j] = pfv[j];

        uint16_t* rh = &ldsA[l*LDSH];
        uint16_t* rl = &ldsA[64*LDSH + l*LDSH];
#pragma unroll
        for (int kk=0; kk<64; kk++){
            float a = (kk<55) ? av[kk] : 0.f;
            uint16_t hi = f2bf(a);
            uint16_t lo = f2bf(a - bf2f(hi));
            rh[kk] = hi; rl[kk] = lo;
        }
        lds_ai[l] = (int)xr[6];
    }
    __syncthreads();

    f32x4 acc[4][4];
    {
        const int lq = l >> 4, lr = l & 15;
#pragma unroll
        for (int mt=0; mt<4; mt++){
#pragma unroll
            for (int r=0; r<4; r++){
                int ai = lds_ai[mt*16 + lq*4 + r];
                const float* ap = app_pre + (size_t)ai*64 + lr;
#pragma unroll
                for (int nt=0; nt<4; nt++)
                    acc[mt][nt][r] = ap[nt*16];
            }
        }
    }
    {
        const int lq = l >> 4, lr = l & 15;
#pragma unroll
        for (int ks=0; ks<2; ks++){
            short8v ah[4], al[4];
#pragma unroll
            for (int mt=0; mt<4; mt++){
                const uint16_t* ph = &ldsA[(mt*16+lr)*LDSH + ks*32 + lq*8];
                ah[mt] = *reinterpret_cast<const short8v*>(ph);
                al[mt] = *reinterpret_cast<const short8v*>(ph + 64*LDSH);
            }
#pragma unroll
            for (int nt=0; nt<4; nt++){
                short8v bh = *reinterpret_cast<const short8v*>(&c0Bhi[(nt*2+ks)*512 + l*8]);
                short8v bl = *reinterpret_cast<const short8v*>(&c0Blo[(nt*2+ks)*512 + l*8]);
#pragma unroll
                for (int mt=0; mt<4; mt++){
                    acc[mt][nt] = __builtin_amdgcn_mfma_f32_16x16x32_bf16(ah[mt], bh, acc[mt][nt], 0,0,0);
                    acc[mt][nt] = __builtin_amdgcn_mfma_f32_16x16x32_bf16(ah[mt], bl, acc[mt][nt], 0,0,0);
                    acc[mt][nt] = __builtin_amdgcn_mfma_f32_16x16x32_bf16(al[mt], bh, acc[mt][nt], 0,0,0);
                }
            }
        }
    }
    __syncthreads();

    {
        const int lq = l >> 4, lr = l & 15;
#pragma unroll
        for (int mt=0; mt<4; mt++){
#pragma unroll
            for (int nt=0; nt<4; nt++){
#pragma unroll
                for (int r=0; r<4; r++){
                    float v = fmaxf(acc[mt][nt][r], 0.f);
                    uint16_t hi = f2bf(v);
                    uint16_t lo = f2bf(v - bf2f(hi));
                    int pt = mt*16 + lq*4 + r;
                    int ch = nt*16 + lr;
                    ldsA[pt*LDSH + ch] = hi;
                    ldsA[64*LDSH + pt*LDSH + ch] = lo;
                }
            }
        }
    }
    __syncthreads();

    {
        const int lq = l >> 4, lr = l & 15;
#pragma unroll
        for (int mt=0; mt<4; mt++)
#pragma unroll
            for (int nt=0; nt<4; nt++){
                acc[mt][nt][0]=0.f; acc[mt][nt][1]=0.f; acc[mt][nt][2]=0.f; acc[mt][nt][3]=0.f;
            }
#pragma unroll
        for (int ks=0; ks<2; ks++){
            short8v ah[4], al[4];
#pragma unroll
            for (int mt=0; mt<4; mt++){
                const uint16_t* ph = &ldsA[(mt*16+lr)*LDSH + ks*32 + lq*8];
                ah[mt] = *reinterpret_cast<const short8v*>(ph);
                al[mt] = *reinterpret_cast<const short8v*>(ph + 64*LDSH);
            }
#pragma unroll
            for (int nt=0; nt<4; nt++){
                short8v bh = *reinterpret_cast<const short8v*>(&c1Bhi[(nt*2+ks)*512 + l*8]);
                short8v bl = *reinterpret_cast<const short8v*>(&c1Blo[(nt*2+ks)*512 + l*8]);
#pragma unroll
                for (int mt=0; mt<4; mt++){
                    acc[mt][nt] = __builtin_amdgcn_mfma_f32_16x16x32_bf16(ah[mt], bh, acc[mt][nt], 0,0,0);
                    acc[mt][nt] = __builtin_amdgcn_mfma_f32_16x16x32_bf16(ah[mt], bl, acc[mt][nt], 0,0,0);
                    acc[mt][nt] = __builtin_amdgcn_mfma_f32_16x16x32_bf16(al[mt], bh, acc[mt][nt], 0,0,0);
                }
            }
        }
    }
    __syncthreads();

    {
        float* ldsF = reinterpret_cast<float*>(ldsA);
        const int lq = l >> 4, lr = l & 15;
#pragma unroll
        for (int mt=0; mt<4; mt++){
#pragma unroll
            for (int nt=0; nt<4; nt++){
#pragma unroll
                for (int r=0; r<4; r++){
                    int pt = mt*16 + lq*4 + r;
                    int ch = nt*16 + lr;
                    ldsF[pt*66 + ch] = fmaxf(acc[mt][nt][r], 0.f);
                }
            }
        }
        __syncthreads();

        float c0=0.f, c1=0.f, c2=0.f;
        const float* row = &ldsF[l*66];
#pragma unroll
        for (int ch=0; ch<64; ch++){
            float v = row[ch];
            float4 w = ld4(&t_c2[ch*4]);
            c0 = fmaf(w.x, v, c0);
            c1 = fmaf(w.y, v, c1);
            c2 = fmaf(w.z, v, c2);
        }
        if (ok){
            float sigma = __uint_as_float(feat[(size_t)15*npts + n]);
            float4 o4;
            o4.x = 1.f/(1.f+expf(-c0));
            o4.y = 1.f/(1.f+expf(-c1));
            o4.z = 1.f/(1.f+expf(-c2));
            o4.w = sigma;
            *reinterpret_cast<float4*>(out + (size_t)n*4) = o4;
        }
    }
}

// ===================== K12m v3: FUSED sigma+color MLP via MFMA =====================
// R10 numerics (3-term hi/lo split in every layer) + color2 as MFMA.
// LDS = hi[64*72] + lo[64*72] + obuf + sig + ai = 19.97KB -> 8 blocks/CU.
__global__ __launch_bounds__(64, 1)
void nerf_k12m(const float* __restrict__ x,
               const float* __restrict__ planes,
               const uint32_t* __restrict__ feat,
               const float* __restrict__ app_pre,
               const short* __restrict__ s0Bhi, const short* __restrict__ s0Blo,
               const short* __restrict__ s1Bhi, const short* __restrict__ s1Blo,
               const short* __restrict__ c0Bhi, const short* __restrict__ c0Blo,
               const short* __restrict__ c1Bhi, const short* __restrict__ c1Blo,
               const short* __restrict__ c2Bhi, const short* __restrict__ c2Blo,
               float* __restrict__ out, int npts)
{
    __shared__ uint16_t ldsA[64*LDSH];   // hi plane (9216 B)
    __shared__ uint16_t ldsB[64*LDSH];   // lo plane (9216 B)
    __shared__ float    obuf[64*4];      // final color scatter (1024 B)
    __shared__ float    sig[64];
    __shared__ int      lds_ai[64];

    const int l = threadIdx.x;
    const int lq = l >> 4, lr = l & 15;
    int n = blockIdx.x*64 + l;
    bool ok = (n < npts);
    int nc = ok ? n : (npts-1);
    const float* xr = x + (size_t)nc*7;

    float pfv[24];
    float sh[16];
    {
        float dx=xr[3], dy=xr[4], dz=xr[5];
        float nrm = sqrtf(dx*dx+dy*dy+dz*dz);
        float sx=dx/nrm, sy=dy/nrm, sz=dz/nrm;
        float xx=sx*sx, yy=sy*sy, zz=sz*sz, xyv=sx*sy, yzv=sy*sz, xzv=sx*sz;
        sh[0]=0.28209479177387814f;
        sh[1]=-0.48860251190291987f*sy;
        sh[2]= 0.48860251190291987f*sz;
        sh[3]=-0.48860251190291987f*sx;
        sh[4]= 1.0925484305920792f*xyv;
        sh[5]=-1.0925484305920792f*yzv;
        sh[6]= 0.94617469575756f*zz-0.31539156525252005f;
        sh[7]=-1.0925484305920792f*xzv;
        sh[8]= 0.5462742152960396f*(xx-yy);
        sh[9]=-0.5900435899266435f*sy*(3.f*xx-yy);
        sh[10]=2.890611442640554f*xyv*sz;
        sh[11]=-0.4570457994644658f*sy*(4.f*zz-xx-yy);
        sh[12]=0.3731763325901154f*sz*(2.f*zz-3.f*xx-3.f*yy);
        sh[13]=-0.4570457994644658f*sx*(4.f*zz-xx-yy);
        sh[14]=1.445305721320277f*sz*(xx-yy);
        sh[15]=-0.5900435899266435f*sx*(xx-3.f*yy);
        plane_enc(planes, (xr[0]+1.f)*0.5f, (xr[1]+1.f)*0.5f, (xr[2]+1.f)*0.5f, pfv);
        lds_ai[l] = (int)xr[6];
    }

    // ---- phase 1: sigma0 A-tile: hash u32-exact (cols 0-31, lo=0), planes hi+lo ----
    {
        uint16_t* rh = &ldsA[l*LDSH];
        uint16_t* rl = &ldsB[l*LDSH];
#pragma unroll
        for (int lv=0; lv<16; lv++){
            *reinterpret_cast<uint32_t*>(&rh[2*lv]) = feat[(size_t)lv*npts + nc];
            *reinterpret_cast<uint32_t*>(&rl[2*lv]) = 0u;
        }
#pragma unroll
        for (int j=0;j<24;j++){
            float a = pfv[j];
            uint16_t hi = f2bf(a);
            rh[32+j] = hi;
            rl[32+j] = f2bf(a - bf2f(hi));
        }
#pragma unroll
        for (int j=56;j<64;j++){ rh[j]=0; rl[j]=0; }
    }
    __syncthreads();

    // ---- phase 2: sigma0 MFMA (3-term; ks=0 A-lo==0 -> skip al term, exact) ----
    f32x4 acc[4][4];
#pragma unroll
    for (int mt=0; mt<4; mt++)
#pragma unroll
        for (int nt=0; nt<4; nt++){
            acc[mt][nt][0]=0.f; acc[mt][nt][1]=0.f; acc[mt][nt][2]=0.f; acc[mt][nt][3]=0.f;
        }
#pragma unroll
    for (int ks=0; ks<2; ks++){
        short8v ah[4], al[4];
#pragma unroll
        for (int mt=0; mt<4; mt++){
            ah[mt] = *reinterpret_cast<const short8v*>(&ldsA[(mt*16+lr)*LDSH + ks*32 + lq*8]);
            al[mt] = *reinterpret_cast<const short8v*>(&ldsB[(mt*16+lr)*LDSH + ks*32 + lq*8]);
        }
#pragma unroll
        for (int nt=0; nt<4; nt++){
            short8v bh = *reinterpret_cast<const short8v*>(&s0Bhi[(nt*2+ks)*512 + l*8]);
            short8v bl = *reinterpret_cast<const short8v*>(&s0Blo[(nt*2+ks)*512 + l*8]);
#pragma unroll
            for (int mt=0; mt<4; mt++){
                acc[mt][nt] = __builtin_amdgcn_mfma_f32_16x16x32_bf16(ah[mt], bh, acc[mt][nt], 0,0,0);
                acc[mt][nt] = __builtin_amdgcn_mfma_f32_16x16x32_bf16(ah[mt], bl, acc[mt][nt], 0,0,0);
                if (ks==1)
                    acc[mt][nt] = __builtin_amdgcn_mfma_f32_16x16x32_bf16(al[mt], bh, acc[mt][nt], 0,0,0);
            }
        }
    }
    __syncthreads();

    // ---- phase 3: relu(h0) repack hi+lo ----
#pragma unroll
    for (int mt=0; mt<4; mt++){
#pragma unroll
        for (int nt=0; nt<4; nt++){
#pragma unroll
            for (int r=0; r<4; r++){
                float v = fmaxf(acc[mt][nt][r], 0.f);
                uint16_t hi = f2bf(v);
                int pt = mt*16 + lq*4 + r;
                int ch = nt*16 + lr;
                ldsA[pt*LDSH + ch] = hi;
                ldsB[pt*LDSH + ch] = f2bf(v - bf2f(hi));
            }
        }
    }
    __syncthreads();

    // ---- phase 4: sigma1 MFMA (3-term, out=16) ----
    f32x4 acc2[4];
#pragma unroll
    for (int mt=0; mt<4; mt++){ acc2[mt][0]=0.f; acc2[mt][1]=0.f; acc2[mt][2]=0.f; acc2[mt][3]=0.f; }
#pragma unroll
    for (int ks=0; ks<2; ks++){
        short8v bh = *reinterpret_cast<const short8v*>(&s1Bhi[ks*512 + l*8]);
        short8v bl = *reinterpret_cast<const short8v*>(&s1Blo[ks*512 + l*8]);
#pragma unroll
        for (int mt=0; mt<4; mt++){
            short8v ah = *reinterpret_cast<const short8v*>(&ldsA[(mt*16+lr)*LDSH + ks*32 + lq*8]);
            short8v al = *reinterpret_cast<const short8v*>(&ldsB[(mt*16+lr)*LDSH + ks*32 + lq*8]);
            acc2[mt] = __builtin_amdgcn_mfma_f32_16x16x32_bf16(ah, bh, acc2[mt], 0,0,0);
            acc2[mt] = __builtin_amdgcn_mfma_f32_16x16x32_bf16(ah, bl, acc2[mt], 0,0,0);
            acc2[mt] = __builtin_amdgcn_mfma_f32_16x16x32_bf16(al, bh, acc2[mt], 0,0,0);
        }
    }
    __syncthreads();

    // ---- phase 5: build color0 A-tile hi+lo: sh 0-15, geo 16-30 (D-scatter), pf 31-54 ----
    {
        uint16_t* rh = &ldsA[l*LDSH];
        uint16_t* rl = &ldsB[l*LDSH];
#pragma unroll
        for (int j=0;j<16;j++){
            float a = sh[j];
            uint16_t hi = f2bf(a);
            rh[j] = hi; rl[j] = f2bf(a - bf2f(hi));
        }
#pragma unroll
        for (int j=0;j<24;j++){
            float a = pfv[j];
            uint16_t hi = f2bf(a);
            rh[31+j] = hi; rl[31+j] = f2bf(a - bf2f(hi));
        }
#pragma unroll
        for (int j=55;j<64;j++){ rh[j]=0; rl[j]=0; }

        int ch = lr;
#pragma unroll
        for (int mt=0; mt<4; mt++){
#pragma unroll
            for (int r=0; r<4; r++){
                int pt = mt*16 + lq*4 + r;
                float v = acc2[mt][r];
                if (ch == 0){
                    sig[pt] = v;
                } else {
                    uint16_t hi = f2bf(v);
                    ldsA[pt*LDSH + 16 + (ch-1)] = hi;
                    ldsB[pt*LDSH + 16 + (ch-1)] = f2bf(v - bf2f(hi));
                }
            }
        }
    }
    __syncthreads();

    // ---- phase 6: color0 MFMA (3-term, app_pre C-init) ----
#pragma unroll
    for (int mt=0; mt<4; mt++){
#pragma unroll
        for (int r=0; r<4; r++){
            int ai = lds_ai[mt*16 + lq*4 + r];
            const float* ap = app_pre + (size_t)ai*64 + lr;
#pragma unroll
            for (int nt=0; nt<4; nt++)
                acc[mt][nt][r] = ap[nt*16];
        }
    }
#pragma unroll
    for (int ks=0; ks<2; ks++){
        short8v ah[4], al[4];
#pragma unroll
        for (int mt=0; mt<4; mt++){
            ah[mt] = *reinterpret_cast<const short8v*>(&ldsA[(mt*16+lr)*LDSH + ks*32 + lq*8]);
            al[mt] = *reinterpret_cast<const short8v*>(&ldsB[(mt*16+lr)*LDSH + ks*32 + lq*8]);
        }
#pragma unroll
        for (int nt=0; nt<4; nt++){
            short8v bh = *reinterpret_cast<const short8v*>(&c0Bhi[(nt*2+ks)*512 + l*8]);
            short8v bl = *reinterpret_cast<const short8v*>(&c0Blo[(nt*2+ks)*512 + l*8]);
#pragma unroll
            for (int mt=0; mt<4; mt++){
                acc[mt][nt] = __builtin_amdgcn_mfma_f32_16x16x32_bf16(ah[mt], bh, acc[mt][nt], 0,0,0);
                acc[mt][nt] = __builtin_amdgcn_mfma_f32_16x16x32_bf16(ah[mt], bl, acc[mt][nt], 0,0,0);
                acc[mt][nt] = __builtin_amdgcn_mfma_f32_16x16x32_bf16(al[mt], bh, acc[mt][nt], 0,0,0);
            }
        }
    }
    __syncthreads();

    // ---- phase 7: relu repack hi+lo; color1 MFMA (3-term) ----
#pragma unroll
    for (int mt=0; mt<4; mt++){
#pragma unroll
        for (int nt=0; nt<4; nt++){
#pragma unroll
            for (int r=0; r<4; r++){
                float v = fmaxf(acc[mt][nt][r], 0.f);
                uint16_t hi = f2bf(v);
                int pt = mt*16 + lq*4 + r;
                int ch = nt*16 + lr;
                ldsA[pt*LDSH + ch] = hi;
                ldsB[pt*LDSH + ch] = f2bf(v - bf2f(hi));
            }
        }
    }
    __syncthreads();

#pragma unroll
    for (int mt=0; mt<4; mt++)
#pragma unroll
        for (int nt=0; nt<4; nt++){
            acc[mt][nt][0]=0.f; acc[mt][nt][1]=0.f; acc[mt][nt][2]=0.f; acc[mt][nt][3]=0.f;
        }
#pragma unroll
    for (int ks=0; ks<2; ks++){
        short8v ah[4], al[4];
#pragma unroll
        for (int mt=0; mt<4; mt++){
            ah[mt] = *reinterpret_cast<const short8v*>(&ldsA[(mt*16+lr)*LDSH + ks*32 + lq*8]);
            al[mt] = *reinterpret_cast<const short8v*>(&ldsB[(mt*16+lr)*LDSH + ks*32 + lq*8]);
        }
#pragma unroll
        for (int nt=0; nt<4; nt++){
            short8v bh = *reinterpret_cast<const short8v*>(&c1Bhi[(nt*2+ks)*512 + l*8]);
            short8v bl = *reinterpret_cast<const short8v*>(&c1Blo[(nt*2+ks)*512 + l*8]);
#pragma unroll
            for (int mt=0; mt<4; mt++){
                acc[mt][nt] = __builtin_amdgcn_mfma_f32_16x16x32_bf16(ah[mt], bh, acc[mt][nt], 0,0,0);
                acc[mt][nt] = __builtin_amdgcn_mfma_f32_16x16x32_bf16(ah[mt], bl, acc[mt][nt], 0,0,0);
                acc[mt][nt] = __builtin_amdgcn_mfma_f32_16x16x32_bf16(al[mt], bh, acc[mt][nt], 0,0,0);
            }
        }
    }
    __syncthreads();

    // ---- phase 8: relu repack hi+lo; color2 MFMA (3-term); scatter; store ----
#pragma unroll
    for (int mt=0; mt<4; mt++){
#pragma unroll
        for (int nt=0; nt<4; nt++){
#pragma unroll
            for (int r=0; r<4; r++){
                float v = fmaxf(acc[mt][nt][r], 0.f);
                uint16_t hi = f2bf(v);
                int pt = mt*16 + lq*4 + r;
                int ch = nt*16 + lr;
                ldsA[pt*LDSH + ch] = hi;
                ldsB[pt*LDSH + ch] = f2bf(v - bf2f(hi));
            }
        }
    }
    __syncthreads();

    f32x4 acc3[4];
#pragma unroll
    for (int mt=0; mt<4; mt++){ acc3[mt][0]=0.f; acc3[mt][1]=0.f; acc3[mt][2]=0.f; acc3[mt][3]=0.f; }
#pragma unroll
    for (int ks=0; ks<2; ks++){
        short8v bh = *reinterpret_cast<const short8v*>(&c2Bhi[ks*512 + l*8]);
        short8v bl = *reinterpret_cast<const short8v*>(&c2Blo[ks*512 + l*8]);
#pragma unroll
        for (int mt=0; mt<4; mt++){
            short8v ah = *reinterpret_cast<const short8v*>(&ldsA[(mt*16+lr)*LDSH + ks*32 + lq*8]);
            short8v al = *reinterpret_cast<const short8v*>(&ldsB[(mt*16+lr)*LDSH + ks*32 + lq*8]);
            acc3[mt] = __builtin_amdgcn_mfma_f32_16x16x32_bf16(ah, bh, acc3[mt], 0,0,0);
            acc3[mt] = __builtin_amdgcn_mfma_f32_16x16x32_bf16(ah, bl, acc3[mt], 0,0,0);
            acc3[mt] = __builtin_amdgcn_mfma_f32_16x16x32_bf16(al, bh, acc3[mt], 0,0,0);
        }
    }
    if (lr < 3){
#pragma unroll
        for (int mt=0; mt<4; mt++){
#pragma unroll
            for (int r=0; r<4; r++){
                obuf[(mt*16 + lq*4 + r)*4 + lr] = acc3[mt][r];
            }
        }
    }
    __syncthreads();

    if (ok){
        float sg = fminf(fmaxf(sig[l], -15.f), 15.f);
        float4 o4;
        o4.x = 1.f/(1.f+expf(-obuf[l*4+0]));
        o4.y = 1.f/(1.f+expf(-obuf[l*4+1]));
        o4.z = 1.f/(1.f+expf(-obuf[l*4+2]));
        o4.w = expf(sg);
        *reinterpret_cast<float4*>(out + (size_t)n*4) = o4;
    }
}

// ===================== fallback single kernel =====================
__global__ __launch_bounds__(256, 1)
void nerf_fwd(const float* __restrict__ x,
              const float* __restrict__ hash_tables,
              const float* __restrict__ planes,
              const float* __restrict__ embed_a,
              const float* __restrict__ w_sigma0,
              const float* __restrict__ w_sigma1,
              const float* __restrict__ w_color0,
              const float* __restrict__ w_color1,
              const float* __restrict__ w_color2,
              float* __restrict__ out,
              ResArr res, int npts)
{
    __shared__ float s_ws0T[56*64];
    __shared__ float s_ws1T[64*16];
    __shared__ float s_wc0T[103*64];
    __shared__ float s_wc1T[64*64];
    __shared__ float s_wc2T[64*4];

    for (int i = threadIdx.x; i < 56*64;  i += 256){ int k=i>>6, o=i&63; s_ws0T[i] = w_sigma0[o*56+k]; }
    for (int i = threadIdx.x; i < 64*16;  i += 256){ int k=i>>4, j=i&15; s_ws1T[i] = w_sigma1[j*64+k]; }
    for (int i = threadIdx.x; i < 103*64; i += 256){ int k=i>>6, o=i&63; s_wc0T[i] = w_color0[o*103+k]; }
    for (int i = threadIdx.x; i < 64*64;  i += 256){ int k=i>>6, o=i&63; s_wc1T[i] = w_color1[o*64+k]; }
    for (int i = threadIdx.x; i < 64*4;   i += 256){ int k=i>>2, o=i&3;  s_wc2T[i] = (o<3)? w_color2[o*64+k] : 0.f; }
    __syncthreads();

    int n = blockIdx.x*256 + threadIdx.x;
    if (n >= npts) return;

    const float* xr = x + (size_t)n*7;
    float px=xr[0], py=xr[1], pz=xr[2];
    float dx=xr[3], dy=xr[4], dz=xr[5];
    float appf = xr[6];
    float p0=(px+1.f)*0.5f, p1=(py+1.f)*0.5f, p2=(pz+1.f)*0.5f;

    float acc[HID];
#pragma unroll
    for (int o=0;o<HID;o++) acc[o]=0.f;

    const float2* tabs = reinterpret_cast<const float2*>(hash_tables);
    for (int l=0; l<NLEV; l++){
        float R = res.v[l];
        float ax=p0*R, ay=p1*R, az=p2*R;
        float fx=floorf(ax), fy=floorf(ay), fz=floorf(az);
        float rx=ax-fx, ry=ay-fy, rz=az-fz;
        uint32_t ix=(uint32_t)fx, iy=(uint32_t)fy, iz=(uint32_t)fz;
        const float2* tab = tabs + (size_t)l*TSIZE;
        uint32_t hx0=ix,               hx1=ix+1u;
        uint32_t hy0=iy*2654435761u,   hy1=(iy+1u)*2654435761u;
        uint32_t hz0=iz*805459861u,    hz1=(iz+1u)*805459861u;
        float wx0=1.f-rx, wx1=rx, wy0=1.f-ry, wy1=ry, wz0=1.f-rz, wz1=rz;
        float f0=0.f, f1=0.f;
#pragma unroll
        for (int c=0;c<8;c++){
            uint32_t hxx=(c&4)?hx1:hx0;
            uint32_t hyy=(c&2)?hy1:hy0;
            uint32_t hzz=(c&1)?hz1:hz0;
            uint32_t idx=(hxx^hyy^hzz)&(TSIZE-1u);
            float2 t = tab[idx];
            float w = ((c&4)?wx1:wx0)*((c&2)?wy1:wy0)*((c&1)?wz1:wz0);
            f0 = fmaf(w,t.x,f0);
            f1 = fmaf(w,t.y,f1);
        }
        AXPY64(acc, &s_ws0T[(2*l+0)*64], f0);
        AXPY64(acc, &s_ws0T[(2*l+1)*64], f1);
    }

    float pfv[24];
    plane_enc(planes, p0, p1, p2, pfv);
#pragma unroll
    for (int j=0;j<24;j++){
        AXPY64(acc, &s_ws0T[(32+j)*64], pfv[j]);
    }

    float h1[16];
#pragma unroll
    for (int j=0;j<16;j++) h1[j]=0.f;
#pragma unroll
    for (int k=0;k<HID;k++){
        float v = fmaxf(acc[k], 0.f);
        const float* wr = &s_ws1T[k*16];
#pragma unroll
        for (int j=0;j<16;j+=4){
            float4 w=ld4(wr+j);
            h1[j+0]=fmaf(w.x,v,h1[j+0]); h1[j+1]=fmaf(w.y,v,h1[j+1]);
            h1[j+2]=fmaf(w.z,v,h1[j+2]); h1[j+3]=fmaf(w.w,v,h1[j+3]);
        }
    }
    float sg = fminf(fmaxf(h1[0], -15.f), 15.f);
    float sigma = expf(sg);

#pragma unroll
    for (int o=0;o<HID;o++) acc[o]=0.f;

    float nrm = sqrtf(dx*dx+dy*dy+dz*dz);
    float sx=dx/nrm, sy=dy/nrm, sz=dz/nrm;
    float xx=sx*sx, yy=sy*sy, zz=sz*sz, xyv=sx*sy, yzv=sy*sz, xzv=sx*sz;
    float sh[16];
    sh[0]=0.28209479177387814f;
    sh[1]=-0.48860251190291987f*sy;
    sh[2]= 0.48860251190291987f*sz;
    sh[3]=-0.48860251190291987f*sx;
    sh[4]= 1.0925484305920792f*xyv;
    sh[5]=-1.0925484305920792f*yzv;
    sh[6]= 0.94617469575756f*zz-0.31539156525252005f;
    sh[7]=-1.0925484305920792f*xzv;
    sh[8]= 0.5462742152960396f*(xx-yy);
    sh[9]=-0.5900435899266435f*sy*(3.f*xx-yy);
    sh[10]=2.890611442640554f*xyv*sz;
    sh[11]=-0.4570457994644658f*sy*(4.f*zz-xx-yy);
    sh[12]=0.3731763325901154f*sz*(2.f*zz-3.f*xx-3.f*yy);
    sh[13]=-0.4570457994644658f*sx*(4.f*zz-xx-yy);
    sh[14]=1.445305721320277f*sz*(xx-yy);
    sh[15]=-0.5900435899266435f*sx*(xx-3.f*yy);
#pragma unroll
    for (int k=0;k<16;k++){
        AXPY64(acc, &s_wc0T[k*64], sh[k]);
    }
#pragma unroll
    for (int j=0;j<15;j++){
        AXPY64(acc, &s_wc0T[(16+j)*64], h1[1+j]);
    }
    {
        int ai = (int)appf;
        const float* ar = embed_a + (size_t)ai*48;
        for (int q=0;q<12;q++){
            float4 av = ld4(ar + q*4);
            const float* wc = &s_wc0T[(31+q*4)*64];
            AXPY64(acc, wc,       av.x);
            AXPY64(acc, wc+64,    av.y);
            AXPY64(acc, wc+128,   av.z);
            AXPY64(acc, wc+192,   av.w);
        }
    }
#pragma unroll
    for (int j=0;j<24;j++){
        AXPY64(acc, &s_wc0T[(79+j)*64], pfv[j]);
    }

    float acc2[HID];
#pragma unroll
    for (int o=0;o<HID;o++) acc2[o]=0.f;
#pragma unroll
    for (int k=0;k<HID;k++){
        float v = fmaxf(acc[k], 0.f);
        AXPY64(acc2, &s_wc1T[k*64], v);
    }

    float c0a=0.f, c1a=0.f, c2a=0.f;
#pragma unroll
    for (int k=0;k<HID;k++){
        float v = fmaxf(acc2[k], 0.f);
        float4 w = ld4(&s_wc2T[k*4]);
        c0a=fmaf(w.x,v,c0a); c1a=fmaf(w.y,v,c1a); c2a=fmaf(w.z,v,c2a);
    }
    float4 o4;
    o4.x = 1.f/(1.f+expf(-c0a));
    o4.y = 1.f/(1.f+expf(-c1a));
    o4.z = 1.f/(1.f+expf(-c2a));
    o4.w = sigma;
    *reinterpret_cast<float4*>(out + (size_t)n*4) = o4;
}

extern "C" void kernel_launch(void* const* d_in, const int* in_sizes, int n_in,
                              void* d_out, int out_size, void* d_ws, size_t ws_size,
                              hipStream_t stream) {
    const float* x        = (const float*)d_in[0];
    const float* ht       = (const float*)d_in[1];
    const float* planes   = (const float*)d_in[2];
    const float* embed_a  = (const float*)d_in[3];
    const float* w_sigma0 = (const float*)d_in[4];
    const float* w_sigma1 = (const float*)d_in[5];
    const float* w_color0 = (const float*)d_in[6];
    const float* w_color1 = (const float*)d_in[7];
    const float* w_color2 = (const float*)d_in[8];
    float* out = (float*)d_out;

    int npts = in_sizes[0] / 7;

    ResArr res;
    double b = exp((log(2048.0) - log(16.0)) / 15.0);
    for (int l=0; l<NLEV; l++)
        res.v[l] = (float)floor(16.0 * pow(b, (double)l));

    // ws layout (bytes)
    const size_t OFF_S0  = 0;
    const size_t OFF_S1  = OFF_S0 + 56*64*4;
    const size_t OFF_C2  = OFF_S1 + 64*16*4;
    const size_t OFF_AP  = OFF_C2 + 64*4*4;
    const size_t OFF_B0H = OFF_AP + 1024*64*4;
    const size_t OFF_B0L = OFF_B0H + 4096*2;
    const size_t OFF_B1H = OFF_B0L + 4096*2;
    const size_t OFF_B1L = OFF_B1H + 4096*2;
    const size_t OFF_SB0H= OFF_B1L + 4096*2;
    const size_t OFF_SB0L= OFF_SB0H + 4096*2;
    const size_t OFF_SB1H= OFF_SB0L + 4096*2;
    const size_t OFF_SB1L= OFF_SB1H + 1024*2;
    const size_t OFF_C2BH= OFF_SB1L + 1024*2;
    const size_t OFF_C2BL= OFF_C2BH + 1024*2;
    const size_t OFF_SMALL_END = OFF_C2BL + 1024*2;
    size_t feat_bytes = (size_t)npts * 16 * sizeof(uint32_t);
    size_t pp_bytes   = (size_t)npts * 16;
    size_t tb_bytes   = (size_t)16 * TSIZE * 4;      // 32MB

    const size_t OFF_PP   = OFF_SMALL_END;
    const size_t OFF_TB   = OFF_PP + pp_bytes;
    const size_t OFF_FEAT2= OFF_TB + tb_bytes;
    const size_t OFF_FEAT1= OFF_SMALL_END;

    bool full_path = (ws_size >= OFF_FEAT2 + feat_bytes);
    bool mid_path  = (ws_size >= OFF_FEAT1 + feat_bytes);

    if (full_path || mid_path) {
        char* base = (char*)d_ws;
        float* t_s0  = (float*)(base + OFF_S0);
        float* t_s1  = (float*)(base + OFF_S1);
        float* t_c2  = (float*)(base + OFF_C2);
        float* a_pre = (float*)(base + OFF_AP);
        short* c0Bhi = (short*)(base + OFF_B0H);
        short* c0Blo = (short*)(base + OFF_B0L);
        short* c1Bhi = (short*)(base + OFF_B1H);
        short* c1Blo = (short*)(base + OFF_B1L);
        short* s0Bhi = (short*)(base + OFF_SB0H);
        short* s0Blo = (short*)(base + OFF_SB0L);
        short* s1Bhi = (short*)(base + OFF_SB1H);
        short* s1Blo = (short*)(base + OFF_SB1L);
        short* c2Bhi = (short*)(base + OFF_C2BH);
        short* c2Blo = (short*)(base + OFF_C2BL);

        hipLaunchKernelGGL(nerf_ktrans, dim3(1), dim3(256), 0, stream,
                           w_sigma0, w_sigma1, w_color0, w_color1, w_color2,
                           t_s0, t_s1, t_c2, c0Bhi, c0Blo, c1Bhi, c1Blo,
                           s0Bhi, s0Blo, s1Bhi, s1Blo, c2Bhi, c2Blo);
        hipLaunchKernelGGL(nerf_kpre, dim3(1024), dim3(64), 0, stream,
                           embed_a, w_color0, a_pre);

        if (full_path) {
            float4*   pp      = (float4*)(base + OFF_PP);
            uint32_t* tabs_bf = (uint32_t*)(base + OFF_TB);
            uint32_t* feat    = (uint32_t*)(base + OFF_FEAT2);

            int total = 16 * (int)TSIZE;
            hipLaunchKernelGGL(nerf_krepack, dim3((total+255)/256), dim3(256), 0, stream,
                               (const float2*)ht, tabs_bf, total);
            hipLaunchKernelGGL(nerf_kprep, dim3((npts+255)/256), dim3(256), 0, stream,
                               x, pp, npts);

            int chunks = (npts + 1023) / 1024;
            hipLaunchKernelGGL(nerf_k0b, dim3(8*chunks), dim3(256), 0, stream,
                               pp, tabs_bf, feat, res, npts, 0);
            hipLaunchKernelGGL(nerf_k0b, dim3(8*chunks), dim3(256), 0, stream,
                               pp, tabs_bf, feat, res, npts, 8);

            int gm = (npts + 63) / 64;
            hipLaunchKernelGGL(nerf_k12m, dim3(gm), dim3(64), 0, stream,
                               x, planes, feat, a_pre,
                               s0Bhi, s0Blo, s1Bhi, s1Blo,
                               c0Bhi, c0Blo, c1Bhi, c1Blo, c2Bhi, c2Blo, out, npts);
        } else {
            uint32_t* feat = (uint32_t*)(base + OFF_FEAT1);
            int chunks = (npts + 511) / 512;
            hipLaunchKernelGGL(nerf_k0, dim3(8*chunks), dim3(256), 0, stream,
                               x, ht, feat, res, npts, 0);
            hipLaunchKernelGGL(nerf_k0, dim3(8*chunks), dim3(256), 0, stream,
                               x, ht, feat, res, npts, 8);
            int g = (npts + 255) / 256;
            hipLaunchKernelGGL(nerf_k1s, dim3(g), dim3(256), 0, stream,
                               x, planes, feat, t_s0, t_s1, npts);
            int gm = (npts + 63) / 64;
            hipLaunchKernelGGL(nerf_k2m, dim3(gm), dim3(64), 0, stream,
                               x, planes, feat, a_pre,
                               c0Bhi, c0Blo, c1Bhi, c1Blo, t_c2, out, npts);
        }
    } else {
        int grid = (npts + 255) / 256;
        hipLaunchKernelGGL(nerf_fwd, dim3(grid), dim3(256), 0, stream,
                           x, ht, planes, embed_a,
                           w_sigma0, w_sigma1, w_color0, w_color1, w_color2,
                           out, res, npts);
    }
}

// Round 13
// 685.863 us; speedup vs baseline: 1.0383x; 1.0383x over previous
//
#include <hip/hip_runtime.h>
#include <cmath>
#include <stdint.h>

#define NLEV  16
#define TSIZE (1u<<19)
#define PRES  512
#define PFD   8
#define HID   64
#define LDSH  72   // short stride per point row in MFMA LDS

struct ResArr { float v[NLEV]; };

typedef __attribute__((ext_vector_type(8))) short short8v;   // 8 bf16 (4 VGPRs)
typedef __attribute__((ext_vector_type(4))) float f32x4;

__device__ __forceinline__ float4 ld4(const float* p){ return *reinterpret_cast<const float4*>(p); }

__device__ __forceinline__ uint16_t f2bf(float f){
    uint32_t u = __float_as_uint(f);
    uint32_t r = (u + 0x7FFFu + ((u>>16)&1u)) >> 16;
    return (uint16_t)r;
}
__device__ __forceinline__ float bf2f(uint32_t h){ return __uint_as_float(h<<16); }

#define AXPY64(A, WPTR, V) do { const float* _w=(WPTR); const float _v=(V); \
  _Pragma("unroll") \
  for (int _o=0;_o<64;_o+=4){ float4 _w4=ld4(_w+_o); \
    A[_o+0]=fmaf(_w4.x,_v,A[_o+0]); A[_o+1]=fmaf(_w4.y,_v,A[_o+1]); \
    A[_o+2]=fmaf(_w4.z,_v,A[_o+2]); A[_o+3]=fmaf(_w4.w,_v,A[_o+3]); } } while(0)

__device__ __forceinline__ void plane_enc(const float* __restrict__ planes,
                                          float p0, float p1, float p2, float* pfv)
{
#pragma unroll
    for (int i=0;i<3;i++){
        float ua = (i==2? p1 : p0)*511.f;
        float va = (i==0? p1 : p2)*511.f;
        float uf=floorf(ua), vf=floorf(va);
        float wu=ua-uf, wv=va-vf;
        int u0=(int)uf; u0 = u0<0?0:(u0>510?510:u0);
        int v0=(int)vf; v0 = v0<0?0:(v0>510?510:v0);
        const float* pl = planes + ((size_t)i*PRES*PRES + (size_t)(u0*PRES+v0))*PFD;
        float4 a0=ld4(pl),              a1=ld4(pl+4);
        float4 b0=ld4(pl+PFD),          b1=ld4(pl+PFD+4);
        float4 c0=ld4(pl+PRES*PFD),     c1=ld4(pl+PRES*PFD+4);
        float4 d0=ld4(pl+PRES*PFD+PFD), d1=ld4(pl+PRES*PFD+PFD+4);
        float w00=(1.f-wu)*(1.f-wv), w01=(1.f-wu)*wv, w10=wu*(1.f-wv), w11=wu*wv;
        pfv[i*8+0]=a0.x*w00+b0.x*w01+c0.x*w10+d0.x*w11;
        pfv[i*8+1]=a0.y*w00+b0.y*w01+c0.y*w10+d0.y*w11;
        pfv[i*8+2]=a0.z*w00+b0.z*w01+c0.z*w10+d0.z*w11;
        pfv[i*8+3]=a0.w*w00+b0.w*w01+c0.w*w10+d0.w*w11;
        pfv[i*8+4]=a1.x*w00+b1.x*w01+c1.x*w10+d1.x*w11;
        pfv[i*8+5]=a1.y*w00+b1.y*w01+c1.y*w10+d1.y*w11;
        pfv[i*8+6]=a1.z*w00+b1.z*w01+c1.z*w10+d1.z*w11;
        pfv[i*8+7]=a1.w*w00+b1.w*w01+c1.w*w10+d1.w*w11;
    }
}

// ===================== krepack: hash tables -> bf16-packed u32 =====================
__global__ void nerf_krepack(const float2* __restrict__ tabs,
                             uint32_t* __restrict__ tabs_bf, int total)
{
    int i = blockIdx.x*256 + threadIdx.x;
    if (i < total){
        float2 t = tabs[i];
        tabs_bf[i] = (uint32_t)f2bf(t.x) | ((uint32_t)f2bf(t.y)<<16);
    }
}

// ===================== kprep: pack (pos01, app) into float4 =====================
__global__ void nerf_kprep(const float* __restrict__ x, float4* __restrict__ pp, int npts)
{
    int n = blockIdx.x*256 + threadIdx.x;
    if (n < npts){
        const float* xr = x + (size_t)n*7;
        pp[n] = make_float4((xr[0]+1.f)*0.5f, (xr[1]+1.f)*0.5f, (xr[2]+1.f)*0.5f, xr[6]);
    }
}

// ===================== K0b: level-major hash gather, bf16 tables, 8 pts/thread ====
// Launched twice (lvl_base 0/8); level = lvl_base+(bid&7) -> 1 level (2MB bf16) per XCD L2.
// 8 pts/thread -> up to 64 outstanding gathers (vmcnt<=63) for latency hiding.
__global__ __launch_bounds__(256, 2)
void nerf_k0b(const float4* __restrict__ pp,
              const uint32_t* __restrict__ tabs_bf,
              uint32_t* __restrict__ feat,
              ResArr res, int npts, int lvl_base)
{
    int bid   = blockIdx.x;
    int level = lvl_base + (bid & 7);
    int chunk = bid >> 3;
    int base_n = chunk*2048 + threadIdx.x;
    float R = res.v[level];
    const uint32_t* tab = tabs_bf + (size_t)level*TSIZE;

    uint32_t g[8][8];
    float rx[8], ry[8], rz[8];
#pragma unroll
    for (int q=0;q<8;q++){
        int n = base_n + q*256;
        int nc = (n < npts) ? n : 0;
        float4 p = pp[nc];
        float ax=p.x*R, ay=p.y*R, az=p.z*R;
        float fx=floorf(ax), fy=floorf(ay), fz=floorf(az);
        rx[q]=ax-fx; ry[q]=ay-fy; rz[q]=az-fz;
        uint32_t ix=(uint32_t)fx, iy=(uint32_t)fy, iz=(uint32_t)fz;
        uint32_t hx0=ix,             hx1=ix+1u;
        uint32_t hy0=iy*2654435761u, hy1=(iy+1u)*2654435761u;
        uint32_t hz0=iz*805459861u,  hz1=(iz+1u)*805459861u;
#pragma unroll
        for (int c=0;c<8;c++){
            uint32_t idx = (((c&4)?hx1:hx0) ^ ((c&2)?hy1:hy0) ^ ((c&1)?hz1:hz0)) & (TSIZE-1u);
            g[q][c] = tab[idx];
        }
    }
#pragma unroll
    for (int q=0;q<8;q++){
        float wx0=1.f-rx[q], wy0=1.f-ry[q], wz0=1.f-rz[q];
        float f0=0.f, f1=0.f;
#pragma unroll
        for (int c=0;c<8;c++){
            float w = ((c&4)?rx[q]:wx0)*((c&2)?ry[q]:wy0)*((c&1)?rz[q]:wz0);
            f0 = fmaf(w, bf2f(g[q][c] & 0xFFFFu), f0);
            f1 = fmaf(w, bf2f(g[q][c] >> 16),     f1);
        }
        int n = base_n + q*256;
        if (n < npts) feat[(size_t)level*npts + n] = (uint32_t)f2bf(f0) | ((uint32_t)f2bf(f1)<<16);
    }
}

// ===================== K0: mid path (fp32 tables) =====================
__global__ __launch_bounds__(256, 2)
void nerf_k0(const float* __restrict__ x,
             const float* __restrict__ hash_tables,
             uint32_t* __restrict__ feat,
             ResArr res, int npts, int lvl_base)
{
    int bid   = blockIdx.x;
    int level = lvl_base + (bid & 7);
    int chunk = bid >> 3;
    int n0 = chunk*512 + threadIdx.x;
    int n1 = n0 + 256;
    float R = res.v[level];
    const float2* tab = reinterpret_cast<const float2*>(hash_tables) + (size_t)level*TSIZE;

    bool v0ok = (n0 < npts), v1ok = (n1 < npts);

    float p0a=0,p1a=0,p2a=0, p0b=0,p1b=0,p2b=0;
    if (v0ok){ const float* xr = x + (size_t)n0*7;
        p0a=(xr[0]+1.f)*0.5f; p1a=(xr[1]+1.f)*0.5f; p2a=(xr[2]+1.f)*0.5f; }
    if (v1ok){ const float* xr = x + (size_t)n1*7;
        p0b=(xr[0]+1.f)*0.5f; p1b=(xr[1]+1.f)*0.5f; p2b=(xr[2]+1.f)*0.5f; }

    float axa=p0a*R, aya=p1a*R, aza=p2a*R;
    float fxa=floorf(axa), fya=floorf(aya), fza=floorf(aza);
    float rxa=axa-fxa, rya=aya-fya, rza=aza-fza;
    uint32_t ixa=(uint32_t)fxa, iya=(uint32_t)fya, iza=(uint32_t)fza;
    uint32_t hx0a=ixa,             hx1a=ixa+1u;
    uint32_t hy0a=iya*2654435761u, hy1a=(iya+1u)*2654435761u;
    uint32_t hz0a=iza*805459861u,  hz1a=(iza+1u)*805459861u;

    float axb=p0b*R, ayb=p1b*R, azb=p2b*R;
    float fxb=floorf(axb), fyb=floorf(ayb), fzb=floorf(azb);
    float rxb=axb-fxb, ryb=ayb-fyb, rzb=azb-fzb;
    uint32_t ixb=(uint32_t)fxb, iyb=(uint32_t)fyb, izb=(uint32_t)fzb;
    uint32_t hx0b=ixb,             hx1b=ixb+1u;
    uint32_t hy0b=iyb*2654435761u, hy1b=(iyb+1u)*2654435761u;
    uint32_t hz0b=izb*805459861u,  hz1b=(izb+1u)*805459861u;

    float2 ta[8], tb[8];
#pragma unroll
    for (int c=0;c<8;c++){
        uint32_t idx = (((c&4)?hx1a:hx0a) ^ ((c&2)?hy1a:hy0a) ^ ((c&1)?hz1a:hz0a)) & (TSIZE-1u);
        ta[c] = tab[idx];
    }
#pragma unroll
    for (int c=0;c<8;c++){
        uint32_t idx = (((c&4)?hx1b:hx0b) ^ ((c&2)?hy1b:hy0b) ^ ((c&1)?hz1b:hz0b)) & (TSIZE-1u);
        tb[c] = tab[idx];
    }

    float wxa0=1.f-rxa, wya0=1.f-rya, wza0=1.f-rza;
    float f0a=0.f, f1a=0.f;
#pragma unroll
    for (int c=0;c<8;c++){
        float w = ((c&4)?rxa:wxa0)*((c&2)?rya:wya0)*((c&1)?rza:wza0);
        f0a = fmaf(w,ta[c].x,f0a); f1a = fmaf(w,ta[c].y,f1a);
    }
    float wxb0=1.f-rxb, wyb0=1.f-ryb, wzb0=1.f-rzb;
    float f0b=0.f, f1b=0.f;
#pragma unroll
    for (int c=0;c<8;c++){
        float w = ((c&4)?rxb:wxb0)*((c&2)?ryb:wyb0)*((c&1)?rzb:wzb0);
        f0b = fmaf(w,tb[c].x,f0b); f1b = fmaf(w,tb[c].y,f1b);
    }

    size_t base = (size_t)level*npts;
    if (v0ok) feat[base+n0] = (uint32_t)f2bf(f0a) | ((uint32_t)f2bf(f1a)<<16);
    if (v1ok) feat[base+n1] = (uint32_t)f2bf(f0b) | ((uint32_t)f2bf(f1b)<<16);
}

// ===================== ktrans: weight prep =====================
// B-fragment layout: idx = nt*1024 + ks*512 + l*8 + i
//   value = w[out = nt*16+(l&15)][k = ks*32+(l>>4)*8+i]
__global__ void nerf_ktrans(const float* __restrict__ w_sigma0,
                            const float* __restrict__ w_sigma1,
                            const float* __restrict__ w_color0,
                            const float* __restrict__ w_color1,
                            const float* __restrict__ w_color2,
                            float* __restrict__ t_s0, float* __restrict__ t_s1,
                            float* __restrict__ t_c2,
                            short* __restrict__ c0Bhi, short* __restrict__ c0Blo,
                            short* __restrict__ c1Bhi, short* __restrict__ c1Blo,
                            short* __restrict__ s0Bhi, short* __restrict__ s0Blo,
                            short* __restrict__ s1Bhi, short* __restrict__ s1Blo,
                            short* __restrict__ c2Bhi, short* __restrict__ c2Blo)
{
    int tid = threadIdx.x;
    for (int i=tid;i<56*64; i+=256){ int k=i>>6,o=i&63; t_s0[i]=w_sigma0[o*56+k]; }
    for (int i=tid;i<64*16; i+=256){ int k=i>>4,j=i&15; t_s1[i]=w_sigma1[j*64+k]; }
    for (int i=tid;i<64*4;  i+=256){ int k=i>>2,o=i&3;  t_c2[i]=(o<3)?w_color2[o*64+k]:0.f; }

    for (int idx=tid; idx<4096; idx+=256){
        int nt = idx >> 10;
        int r1 = idx & 1023;
        int ks = r1 >> 9;
        int r2 = r1 & 511;
        int l  = r2 >> 3;
        int i  = r2 & 7;
        int out = nt*16 + (l & 15);
        int kk  = ks*32 + (l >> 4)*8 + i;
        float w0 = 0.f;
        if (kk < 31)       w0 = w_color0[out*103 + kk];
        else if (kk < 55)  w0 = w_color0[out*103 + kk + 48];
        uint16_t h0 = f2bf(w0);
        uint16_t l0 = f2bf(w0 - bf2f(h0));
        c0Bhi[idx] = (short)h0; c0Blo[idx] = (short)l0;
        float w1 = w_color1[out*64 + kk];
        uint16_t h1 = f2bf(w1);
        uint16_t l1 = f2bf(w1 - bf2f(h1));
        c1Bhi[idx] = (short)h1; c1Blo[idx] = (short)l1;
        float ws = (kk < 56) ? w_sigma0[out*56 + kk] : 0.f;
        uint16_t hs = f2bf(ws);
        uint16_t ls = f2bf(ws - bf2f(hs));
        s0Bhi[idx] = (short)hs; s0Blo[idx] = (short)ls;
    }
    // sigma1 (out=16) and color2 (out=3): 1 nt tile, idx = ks*512 + l*8 + i
    for (int idx=tid; idx<1024; idx+=256){
        int ks = idx >> 9;
        int r2 = idx & 511;
        int l  = r2 >> 3;
        int i  = r2 & 7;
        int out = l & 15;
        int kk  = ks*32 + (l >> 4)*8 + i;
        float w = w_sigma1[out*64 + kk];
        uint16_t h = f2bf(w);
        s1Bhi[idx] = (short)h; s1Blo[idx] = (short)f2bf(w - bf2f(h));
        float wc = (out < 3) ? w_color2[out*64 + kk] : 0.f;
        uint16_t hc2 = f2bf(wc);
        c2Bhi[idx] = (short)hc2; c2Blo[idx] = (short)f2bf(wc - bf2f(hc2));
    }
}

// ===================== kpre: app_pre[a][o] =====================
__global__ void nerf_kpre(const float* __restrict__ embed_a,
                          const float* __restrict__ w_color0,
                          float* __restrict__ app_pre)
{
    int a = blockIdx.x;
    int o = threadIdx.x;   // 64
    const float* er = embed_a + (size_t)a*48;
    const float* wr = w_color0 + (size_t)o*103 + 31;
    float s = 0.f;
#pragma unroll
    for (int j=0;j<48;j++) s = fmaf(er[j], wr[j], s);
    app_pre[(size_t)a*64 + o] = s;
}

// ===================== K1s: mid-path sigma MLP (VALU) =====================
__global__ __launch_bounds__(256, 2)
void nerf_k1s(const float* __restrict__ x,
              const float* __restrict__ planes,
              uint32_t* __restrict__ feat,
              const float* __restrict__ wT_s0,
              const float* __restrict__ wT_s1,
              int npts)
{
    int n = blockIdx.x*256 + threadIdx.x;
    if (n >= npts) return;

    uint32_t fl[NLEV];
#pragma unroll
    for (int l=0;l<NLEV;l++) fl[l] = feat[(size_t)l*npts + n];

    float acc[HID];
#pragma unroll
    for (int o=0;o<HID;o++) acc[o]=0.f;

#pragma unroll
    for (int l=0;l<NLEV;l++){
        float f0 = bf2f(fl[l] & 0xFFFFu);
        float f1 = bf2f(fl[l] >> 16);
        AXPY64(acc, &wT_s0[(2*l+0)*64], f0);
        AXPY64(acc, &wT_s0[(2*l+1)*64], f1);
    }

    const float* xr = x + (size_t)n*7;
    float p0=(xr[0]+1.f)*0.5f, p1=(xr[1]+1.f)*0.5f, p2=(xr[2]+1.f)*0.5f;
    float pfv[24];
    plane_enc(planes, p0, p1, p2, pfv);
#pragma unroll
    for (int j=0;j<24;j++){
        AXPY64(acc, &wT_s0[(32+j)*64], pfv[j]);
    }

    float h1[16];
#pragma unroll
    for (int j=0;j<16;j++) h1[j]=0.f;
#pragma unroll
    for (int k=0;k<HID;k++){
        float v = fmaxf(acc[k], 0.f);
        const float* wr = &wT_s1[k*16];
#pragma unroll
        for (int j=0;j<16;j+=4){
            float4 w=ld4(wr+j);
            h1[j+0]=fmaf(w.x,v,h1[j+0]); h1[j+1]=fmaf(w.y,v,h1[j+1]);
            h1[j+2]=fmaf(w.z,v,h1[j+2]); h1[j+3]=fmaf(w.w,v,h1[j+3]);
        }
    }
    float sg = fminf(fmaxf(h1[0], -15.f), 15.f);
    float sigma = expf(sg);

#pragma unroll
    for (int l=0;l<15;l++) feat[(size_t)l*npts + n] = __float_as_uint(h1[l+1]);
    feat[(size_t)15*npts + n] = __float_as_uint(sigma);
}

// ===================== K2m: mid-path color MLP (MFMA, R8-verified) =====================
__global__ __launch_bounds__(64, 1)
void nerf_k2m(const float* __restrict__ x,
              const float* __restrict__ planes,
              const uint32_t* __restrict__ feat,
              const float* __restrict__ app_pre,
              const short* __restrict__ c0Bhi, const short* __restrict__ c0Blo,
              const short* __restrict__ c1Bhi, const short* __restrict__ c1Blo,
              const float* __restrict__ t_c2,
              float* __restrict__ out, int npts)
{
    __shared__ uint16_t ldsA[2*64*LDSH];
    __shared__ int      lds_ai[64];

    const int l = threadIdx.x;
    int n = blockIdx.x*64 + l;
    bool ok = (n < npts);
    int nc = ok ? n : (npts-1);
    const float* xr = x + (size_t)nc*7;

    {
        float av[55];
        float dx=xr[3], dy=xr[4], dz=xr[5];
        float nrm = sqrtf(dx*dx+dy*dy+dz*dz);
        float sx=dx/nrm, sy=dy/nrm, sz=dz/nrm;
        float xx=sx*sx, yy=sy*sy, zz=sz*sz, xyv=sx*sy, yzv=sy*sz, xzv=sx*sz;
        av[0]=0.28209479177387814f;
        av[1]=-0.48860251190291987f*sy;
        av[2]= 0.48860251190291987f*sz;
        av[3]=-0.48860251190291987f*sx;
        av[4]= 1.0925484305920792f*xyv;
        av[5]=-1.0925484305920792f*yzv;
        av[6]= 0.94617469575756f*zz-0.31539156525252005f;
        av[7]=-1.0925484305920792f*xzv;
        av[8]= 0.5462742152960396f*(xx-yy);
        av[9]=-0.5900435899266435f*sy*(3.f*xx-yy);
        av[10]=2.890611442640554f*xyv*sz;
        av[11]=-0.4570457994644658f*sy*(4.f*zz-xx-yy);
        av[12]=0.3731763325901154f*sz*(2.f*zz-3.f*xx-3.f*yy);
        av[13]=-0.4570457994644658f*sx*(4.f*zz-xx-yy);
        av[14]=1.445305721320277f*sz*(xx-yy);
        av[15]=-0.5900435899266435f*sx*(xx-3.f*yy);
#pragma unroll
        for (int j=0;j<15;j++) av[16+j] = __uint_as_float(feat[(size_t)j*npts + nc]);
        float pfv[24];
        plane_enc(planes, (xr[0]+1.f)*0.5f, (xr[1]+1.f)*0.5f, (xr[2]+1.f)*0.5f, pfv);
#pragma unroll
        for (int j=0;j<24;j++) av[31+j] = pfv[j];

        uint16_t* rh = &ldsA[l*LDSH];
        uint16_t* rl = &ldsA[64*LDSH + l*LDSH];
#pragma unroll
        for (int kk=0; kk<64; kk++){
            float a = (kk<55) ? av[kk] : 0.f;
            uint16_t hi = f2bf(a);
            uint16_t lo = f2bf(a - bf2f(hi));
            rh[kk] = hi; rl[kk] = lo;
        }
        lds_ai[l] = (int)xr[6];
    }
    __syncthreads();

    f32x4 acc[4][4];
    {
        const int lq = l >> 4, lr = l & 15;
#pragma unroll
        for (int mt=0; mt<4; mt++){
#pragma unroll
            for (int r=0; r<4; r++){
                int ai = lds_ai[mt*16 + lq*4 + r];
                const float* ap = app_pre + (size_t)ai*64 + lr;
#pragma unroll
                for (int nt=0; nt<4; nt++)
                    acc[mt][nt][r] = ap[nt*16];
            }
        }
    }
    {
        const int lq = l >> 4, lr = l & 15;
#pragma unroll
        for (int ks=0; ks<2; ks++){
            short8v ah[4], al[4];
#pragma unroll
            for (int mt=0; mt<4; mt++){
                const uint16_t* ph = &ldsA[(mt*16+lr)*LDSH + ks*32 + lq*8];
                ah[mt] = *reinterpret_cast<const short8v*>(ph);
                al[mt] = *reinterpret_cast<const short8v*>(ph + 64*LDSH);
            }
#pragma unroll
            for (int nt=0; nt<4; nt++){
                short8v bh = *reinterpret_cast<const short8v*>(&c0Bhi[(nt*2+ks)*512 + l*8]);
                short8v bl = *reinterpret_cast<const short8v*>(&c0Blo[(nt*2+ks)*512 + l*8]);
#pragma unroll
                for (int mt=0; mt<4; mt++){
                    acc[mt][nt] = __builtin_amdgcn_mfma_f32_16x16x32_bf16(ah[mt], bh, acc[mt][nt], 0,0,0);
                    acc[mt][nt] = __builtin_amdgcn_mfma_f32_16x16x32_bf16(ah[mt], bl, acc[mt][nt], 0,0,0);
                    acc[mt][nt] = __builtin_amdgcn_mfma_f32_16x16x32_bf16(al[mt], bh, acc[mt][nt], 0,0,0);
                }
            }
        }
    }
    __syncthreads();

    {
        const int lq = l >> 4, lr = l & 15;
#pragma unroll
        for (int mt=0; mt<4; mt++){
#pragma unroll
            for (int nt=0; nt<4; nt++){
#pragma unroll
                for (int r=0; r<4; r++){
                    float v = fmaxf(acc[mt][nt][r], 0.f);
                    uint16_t hi = f2bf(v);
                    uint16_t lo = f2bf(v - bf2f(hi));
                    int pt = mt*16 + lq*4 + r;
                    int ch = nt*16 + lr;
                    ldsA[pt*LDSH + ch] = hi;
                    ldsA[64*LDSH + pt*LDSH + ch] = lo;
                }
            }
        }
    }
    __syncthreads();

    {
        const int lq = l >> 4, lr = l & 15;
#pragma unroll
        for (int mt=0; mt<4; mt++)
#pragma unroll
            for (int nt=0; nt<4; nt++){
                acc[mt][nt][0]=0.f; acc[mt][nt][1]=0.f; acc[mt][nt][2]=0.f; acc[mt][nt][3]=0.f;
            }
#pragma unroll
        for (int ks=0; ks<2; ks++){
            short8v ah[4], al[4];
#pragma unroll
            for (int mt=0; mt<4; mt++){
                const uint16_t* ph = &ldsA[(mt*16+lr)*LDSH + ks*32 + lq*8];
                ah[mt] = *reinterpret_cast<const short8v*>(ph);
                al[mt] = *reinterpret_cast<const short8v*>(ph + 64*LDSH);
            }
#pragma unroll
            for (int nt=0; nt<4; nt++){
                short8v bh = *reinterpret_cast<const short8v*>(&c1Bhi[(nt*2+ks)*512 + l*8]);
                short8v bl = *reinterpret_cast<const short8v*>(&c1Blo[(nt*2+ks)*512 + l*8]);
#pragma unroll
                for (int mt=0; mt<4; mt++){
                    acc[mt][nt] = __builtin_amdgcn_mfma_f32_16x16x32_bf16(ah[mt], bh, acc[mt][nt], 0,0,0);
                    acc[mt][nt] = __builtin_amdgcn_mfma_f32_16x16x32_bf16(ah[mt], bl, acc[mt][nt], 0,0,0);
                    acc[mt][nt] = __builtin_amdgcn_mfma_f32_16x16x32_bf16(al[mt], bh, acc[mt][nt], 0,0,0);
                }
            }
        }
    }
    __syncthreads();

    {
        float* ldsF = reinterpret_cast<float*>(ldsA);
        const int lq = l >> 4, lr = l & 15;
#pragma unroll
        for (int mt=0; mt<4; mt++){
#pragma unroll
            for (int nt=0; nt<4; nt++){
#pragma unroll
                for (int r=0; r<4; r++){
                    int pt = mt*16 + lq*4 + r;
                    int ch = nt*16 + lr;
                    ldsF[pt*66 + ch] = fmaxf(acc[mt][nt][r], 0.f);
                }
            }
        }
        __syncthreads();

        float c0=0.f, c1=0.f, c2=0.f;
        const float* row = &ldsF[l*66];
#pragma unroll
        for (int ch=0; ch<64; ch++){
            float v = row[ch];
            float4 w = ld4(&t_c2[ch*4]);
            c0 = fmaf(w.x, v, c0);
            c1 = fmaf(w.y, v, c1);
            c2 = fmaf(w.z, v, c2);
        }
        if (ok){
            float sigma = __uint_as_float(feat[(size_t)15*npts + n]);
            float4 o4;
            o4.x = 1.f/(1.f+expf(-c0));
            o4.y = 1.f/(1.f+expf(-c1));
            o4.z = 1.f/(1.f+expf(-c2));
            o4.w = sigma;
            *reinterpret_cast<float4*>(out + (size_t)n*4) = o4;
        }
    }
}

// ===================== K12m v3: FUSED sigma+color MLP via MFMA (R12-verified) =====================
__global__ __launch_bounds__(64, 1)
void nerf_k12m(const float* __restrict__ x,
               const float* __restrict__ planes,
               const uint32_t* __restrict__ feat,
               const float* __restrict__ app_pre,
               const short* __restrict__ s0Bhi, const short* __restrict__ s0Blo,
               const short* __restrict__ s1Bhi, const short* __restrict__ s1Blo,
               const short* __restrict__ c0Bhi, const short* __restrict__ c0Blo,
               const short* __restrict__ c1Bhi, const short* __restrict__ c1Blo,
               const short* __restrict__ c2Bhi, const short* __restrict__ c2Blo,
               float* __restrict__ out, int npts)
{
    __shared__ uint16_t ldsA[64*LDSH];   // hi plane (9216 B)
    __shared__ uint16_t ldsB[64*LDSH];   // lo plane (9216 B)
    __shared__ float    obuf[64*4];
    __shared__ float    sig[64];
    __shared__ int      lds_ai[64];

    const int l = threadIdx.x;
    const int lq = l >> 4, lr = l & 15;
    int n = blockIdx.x*64 + l;
    bool ok = (n < npts);
    int nc = ok ? n : (npts-1);
    const float* xr = x + (size_t)nc*7;

    float pfv[24];
    float sh[16];
    {
        float dx=xr[3], dy=xr[4], dz=xr[5];
        float nrm = sqrtf(dx*dx+dy*dy+dz*dz);
        float sx=dx/nrm, sy=dy/nrm, sz=dz/nrm;
        float xx=sx*sx, yy=sy*sy, zz=sz*sz, xyv=sx*sy, yzv=sy*sz, xzv=sx*sz;
        sh[0]=0.28209479177387814f;
        sh[1]=-0.48860251190291987f*sy;
        sh[2]= 0.48860251190291987f*sz;
        sh[3]=-0.48860251190291987f*sx;
        sh[4]= 1.0925484305920792f*xyv;
        sh[5]=-1.0925484305920792f*yzv;
        sh[6]= 0.94617469575756f*zz-0.31539156525252005f;
        sh[7]=-1.0925484305920792f*xzv;
        sh[8]= 0.5462742152960396f*(xx-yy);
        sh[9]=-0.5900435899266435f*sy*(3.f*xx-yy);
        sh[10]=2.890611442640554f*xyv*sz;
        sh[11]=-0.4570457994644658f*sy*(4.f*zz-xx-yy);
        sh[12]=0.3731763325901154f*sz*(2.f*zz-3.f*xx-3.f*yy);
        sh[13]=-0.4570457994644658f*sx*(4.f*zz-xx-yy);
        sh[14]=1.445305721320277f*sz*(xx-yy);
        sh[15]=-0.5900435899266435f*sx*(xx-3.f*yy);
        plane_enc(planes, (xr[0]+1.f)*0.5f, (xr[1]+1.f)*0.5f, (xr[2]+1.f)*0.5f, pfv);
        lds_ai[l] = (int)xr[6];
    }

    // ---- phase 1: sigma0 A-tile: hash u32-exact (cols 0-31, lo=0), planes hi+lo ----
    {
        uint16_t* rh = &ldsA[l*LDSH];
        uint16_t* rl = &ldsB[l*LDSH];
#pragma unroll
        for (int lv=0; lv<16; lv++){
            *reinterpret_cast<uint32_t*>(&rh[2*lv]) = feat[(size_t)lv*npts + nc];
            *reinterpret_cast<uint32_t*>(&rl[2*lv]) = 0u;
        }
#pragma unroll
        for (int j=0;j<24;j++){
            float a = pfv[j];
            uint16_t hi = f2bf(a);
            rh[32+j] = hi;
            rl[32+j] = f2bf(a - bf2f(hi));
        }
#pragma unroll
        for (int j=56;j<64;j++){ rh[j]=0; rl[j]=0; }
    }
    __syncthreads();

    // ---- phase 2: sigma0 MFMA (3-term; ks=0 A-lo==0 -> skip al term, exact) ----
    f32x4 acc[4][4];
#pragma unroll
    for (int mt=0; mt<4; mt++)
#pragma unroll
        for (int nt=0; nt<4; nt++){
            acc[mt][nt][0]=0.f; acc[mt][nt][1]=0.f; acc[mt][nt][2]=0.f; acc[mt][nt][3]=0.f;
        }
#pragma unroll
    for (int ks=0; ks<2; ks++){
        short8v ah[4], al[4];
#pragma unroll
        for (int mt=0; mt<4; mt++){
            ah[mt] = *reinterpret_cast<const short8v*>(&ldsA[(mt*16+lr)*LDSH + ks*32 + lq*8]);
            al[mt] = *reinterpret_cast<const short8v*>(&ldsB[(mt*16+lr)*LDSH + ks*32 + lq*8]);
        }
#pragma unroll
        for (int nt=0; nt<4; nt++){
            short8v bh = *reinterpret_cast<const short8v*>(&s0Bhi[(nt*2+ks)*512 + l*8]);
            short8v bl = *reinterpret_cast<const short8v*>(&s0Blo[(nt*2+ks)*512 + l*8]);
#pragma unroll
            for (int mt=0; mt<4; mt++){
                acc[mt][nt] = __builtin_amdgcn_mfma_f32_16x16x32_bf16(ah[mt], bh, acc[mt][nt], 0,0,0);
                acc[mt][nt] = __builtin_amdgcn_mfma_f32_16x16x32_bf16(ah[mt], bl, acc[mt][nt], 0,0,0);
                if (ks==1)
                    acc[mt][nt] = __builtin_amdgcn_mfma_f32_16x16x32_bf16(al[mt], bh, acc[mt][nt], 0,0,0);
            }
        }
    }
    __syncthreads();

    // ---- phase 3: relu(h0) repack hi+lo ----
#pragma unroll
    for (int mt=0; mt<4; mt++){
#pragma unroll
        for (int nt=0; nt<4; nt++){
#pragma unroll
            for (int r=0; r<4; r++){
                float v = fmaxf(acc[mt][nt][r], 0.f);
                uint16_t hi = f2bf(v);
                int pt = mt*16 + lq*4 + r;
                int ch = nt*16 + lr;
                ldsA[pt*LDSH + ch] = hi;
                ldsB[pt*LDSH + ch] = f2bf(v - bf2f(hi));
            }
        }
    }
    __syncthreads();

    // ---- phase 4: sigma1 MFMA (3-term, out=16) ----
    f32x4 acc2[4];
#pragma unroll
    for (int mt=0; mt<4; mt++){ acc2[mt][0]=0.f; acc2[mt][1]=0.f; acc2[mt][2]=0.f; acc2[mt][3]=0.f; }
#pragma unroll
    for (int ks=0; ks<2; ks++){
        short8v bh = *reinterpret_cast<const short8v*>(&s1Bhi[ks*512 + l*8]);
        short8v bl = *reinterpret_cast<const short8v*>(&s1Blo[ks*512 + l*8]);
#pragma unroll
        for (int mt=0; mt<4; mt++){
            short8v ah = *reinterpret_cast<const short8v*>(&ldsA[(mt*16+lr)*LDSH + ks*32 + lq*8]);
            short8v al = *reinterpret_cast<const short8v*>(&ldsB[(mt*16+lr)*LDSH + ks*32 + lq*8]);
            acc2[mt] = __builtin_amdgcn_mfma_f32_16x16x32_bf16(ah, bh, acc2[mt], 0,0,0);
            acc2[mt] = __builtin_amdgcn_mfma_f32_16x16x32_bf16(ah, bl, acc2[mt], 0,0,0);
            acc2[mt] = __builtin_amdgcn_mfma_f32_16x16x32_bf16(al, bh, acc2[mt], 0,0,0);
        }
    }
    __syncthreads();

    // ---- phase 5: build color0 A-tile hi+lo: sh 0-15, geo 16-30 (D-scatter), pf 31-54 ----
    {
        uint16_t* rh = &ldsA[l*LDSH];
        uint16_t* rl = &ldsB[l*LDSH];
#pragma unroll
        for (int j=0;j<16;j++){
            float a = sh[j];
            uint16_t hi = f2bf(a);
            rh[j] = hi; rl[j] = f2bf(a - bf2f(hi));
        }
#pragma unroll
        for (int j=0;j<24;j++){
            float a = pfv[j];
            uint16_t hi = f2bf(a);
            rh[31+j] = hi; rl[31+j] = f2bf(a - bf2f(hi));
        }
#pragma unroll
        for (int j=55;j<64;j++){ rh[j]=0; rl[j]=0; }

        int ch = lr;
#pragma unroll
        for (int mt=0; mt<4; mt++){
#pragma unroll
            for (int r=0; r<4; r++){
                int pt = mt*16 + lq*4 + r;
                float v = acc2[mt][r];
                if (ch == 0){
                    sig[pt] = v;
                } else {
                    uint16_t hi = f2bf(v);
                    ldsA[pt*LDSH + 16 + (ch-1)] = hi;
                    ldsB[pt*LDSH + 16 + (ch-1)] = f2bf(v - bf2f(hi));
                }
            }
        }
    }
    __syncthreads();

    // ---- phase 6: color0 MFMA (3-term, app_pre C-init) ----
#pragma unroll
    for (int mt=0; mt<4; mt++){
#pragma unroll
        for (int r=0; r<4; r++){
            int ai = lds_ai[mt*16 + lq*4 + r];
            const float* ap = app_pre + (size_t)ai*64 + lr;
#pragma unroll
            for (int nt=0; nt<4; nt++)
                acc[mt][nt][r] = ap[nt*16];
        }
    }
#pragma unroll
    for (int ks=0; ks<2; ks++){
        short8v ah[4], al[4];
#pragma unroll
        for (int mt=0; mt<4; mt++){
            ah[mt] = *reinterpret_cast<const short8v*>(&ldsA[(mt*16+lr)*LDSH + ks*32 + lq*8]);
            al[mt] = *reinterpret_cast<const short8v*>(&ldsB[(mt*16+lr)*LDSH + ks*32 + lq*8]);
        }
#pragma unroll
        for (int nt=0; nt<4; nt++){
            short8v bh = *reinterpret_cast<const short8v*>(&c0Bhi[(nt*2+ks)*512 + l*8]);
            short8v bl = *reinterpret_cast<const short8v*>(&c0Blo[(nt*2+ks)*512 + l*8]);
#pragma unroll
            for (int mt=0; mt<4; mt++){
                acc[mt][nt] = __builtin_amdgcn_mfma_f32_16x16x32_bf16(ah[mt], bh, acc[mt][nt], 0,0,0);
                acc[mt][nt] = __builtin_amdgcn_mfma_f32_16x16x32_bf16(ah[mt], bl, acc[mt][nt], 0,0,0);
                acc[mt][nt] = __builtin_amdgcn_mfma_f32_16x16x32_bf16(al[mt], bh, acc[mt][nt], 0,0,0);
            }
        }
    }
    __syncthreads();

    // ---- phase 7: relu repack hi+lo; color1 MFMA (3-term) ----
#pragma unroll
    for (int mt=0; mt<4; mt++){
#pragma unroll
        for (int nt=0; nt<4; nt++){
#pragma unroll
            for (int r=0; r<4; r++){
                float v = fmaxf(acc[mt][nt][r], 0.f);
                uint16_t hi = f2bf(v);
                int pt = mt*16 + lq*4 + r;
                int ch = nt*16 + lr;
                ldsA[pt*LDSH + ch] = hi;
                ldsB[pt*LDSH + ch] = f2bf(v - bf2f(hi));
            }
        }
    }
    __syncthreads();

#pragma unroll
    for (int mt=0; mt<4; mt++)
#pragma unroll
        for (int nt=0; nt<4; nt++){
            acc[mt][nt][0]=0.f; acc[mt][nt][1]=0.f; acc[mt][nt][2]=0.f; acc[mt][nt][3]=0.f;
        }
#pragma unroll
    for (int ks=0; ks<2; ks++){
        short8v ah[4], al[4];
#pragma unroll
        for (int mt=0; mt<4; mt++){
            ah[mt] = *reinterpret_cast<const short8v*>(&ldsA[(mt*16+lr)*LDSH + ks*32 + lq*8]);
            al[mt] = *reinterpret_cast<const short8v*>(&ldsB[(mt*16+lr)*LDSH + ks*32 + lq*8]);
        }
#pragma unroll
        for (int nt=0; nt<4; nt++){
            short8v bh = *reinterpret_cast<const short8v*>(&c1Bhi[(nt*2+ks)*512 + l*8]);
            short8v bl = *reinterpret_cast<const short8v*>(&c1Blo[(nt*2+ks)*512 + l*8]);
#pragma unroll
            for (int mt=0; mt<4; mt++){
                acc[mt][nt] = __builtin_amdgcn_mfma_f32_16x16x32_bf16(ah[mt], bh, acc[mt][nt], 0,0,0);
                acc[mt][nt] = __builtin_amdgcn_mfma_f32_16x16x32_bf16(ah[mt], bl, acc[mt][nt], 0,0,0);
                acc[mt][nt] = __builtin_amdgcn_mfma_f32_16x16x32_bf16(al[mt], bh, acc[mt][nt], 0,0,0);
            }
        }
    }
    __syncthreads();

    // ---- phase 8: relu repack hi+lo; color2 MFMA (3-term); scatter; store ----
#pragma unroll
    for (int mt=0; mt<4; mt++){
#pragma unroll
        for (int nt=0; nt<4; nt++){
#pragma unroll
            for (int r=0; r<4; r++){
                float v = fmaxf(acc[mt][nt][r], 0.f);
                uint16_t hi = f2bf(v);
                int pt = mt*16 + lq*4 + r;
                int ch = nt*16 + lr;
                ldsA[pt*LDSH + ch] = hi;
                ldsB[pt*LDSH + ch] = f2bf(v - bf2f(hi));
            }
        }
    }
    __syncthreads();

    f32x4 acc3[4];
#pragma unroll
    for (int mt=0; mt<4; mt++){ acc3[mt][0]=0.f; acc3[mt][1]=0.f; acc3[mt][2]=0.f; acc3[mt][3]=0.f; }
#pragma unroll
    for (int ks=0; ks<2; ks++){
        short8v bh = *reinterpret_cast<const short8v*>(&c2Bhi[ks*512 + l*8]);
        short8v bl = *reinterpret_cast<const short8v*>(&c2Blo[ks*512 + l*8]);
#pragma unroll
        for (int mt=0; mt<4; mt++){
            short8v ah = *reinterpret_cast<const short8v*>(&ldsA[(mt*16+lr)*LDSH + ks*32 + lq*8]);
            short8v al = *reinterpret_cast<const short8v*>(&ldsB[(mt*16+lr)*LDSH + ks*32 + lq*8]);
            acc3[mt] = __builtin_amdgcn_mfma_f32_16x16x32_bf16(ah, bh, acc3[mt], 0,0,0);
            acc3[mt] = __builtin_amdgcn_mfma_f32_16x16x32_bf16(ah, bl, acc3[mt], 0,0,0);
            acc3[mt] = __builtin_amdgcn_mfma_f32_16x16x32_bf16(al, bh, acc3[mt], 0,0,0);
        }
    }
    if (lr < 3){
#pragma unroll
        for (int mt=0; mt<4; mt++){
#pragma unroll
            for (int r=0; r<4; r++){
                obuf[(mt*16 + lq*4 + r)*4 + lr] = acc3[mt][r];
            }
        }
    }
    __syncthreads();

    if (ok){
        float sg = fminf(fmaxf(sig[l], -15.f), 15.f);
        float4 o4;
        o4.x = 1.f/(1.f+expf(-obuf[l*4+0]));
        o4.y = 1.f/(1.f+expf(-obuf[l*4+1]));
        o4.z = 1.f/(1.f+expf(-obuf[l*4+2]));
        o4.w = expf(sg);
        *reinterpret_cast<float4*>(out + (size_t)n*4) = o4;
    }
}

// ===================== fallback single kernel =====================
__global__ __launch_bounds__(256, 1)
void nerf_fwd(const float* __restrict__ x,
              const float* __restrict__ hash_tables,
              const float* __restrict__ planes,
              const float* __restrict__ embed_a,
              const float* __restrict__ w_sigma0,
              const float* __restrict__ w_sigma1,
              const float* __restrict__ w_color0,
              const float* __restrict__ w_color1,
              const float* __restrict__ w_color2,
              float* __restrict__ out,
              ResArr res, int npts)
{
    __shared__ float s_ws0T[56*64];
    __shared__ float s_ws1T[64*16];
    __shared__ float s_wc0T[103*64];
    __shared__ float s_wc1T[64*64];
    __shared__ float s_wc2T[64*4];

    for (int i = threadIdx.x; i < 56*64;  i += 256){ int k=i>>6, o=i&63; s_ws0T[i] = w_sigma0[o*56+k]; }
    for (int i = threadIdx.x; i < 64*16;  i += 256){ int k=i>>4, j=i&15; s_ws1T[i] = w_sigma1[j*64+k]; }
    for (int i = threadIdx.x; i < 103*64; i += 256){ int k=i>>6, o=i&63; s_wc0T[i] = w_color0[o*103+k]; }
    for (int i = threadIdx.x; i < 64*64;  i += 256){ int k=i>>6, o=i&63; s_wc1T[i] = w_color1[o*64+k]; }
    for (int i = threadIdx.x; i < 64*4;   i += 256){ int k=i>>2, o=i&3;  s_wc2T[i] = (o<3)? w_color2[o*64+k] : 0.f; }
    __syncthreads();

    int n = blockIdx.x*256 + threadIdx.x;
    if (n >= npts) return;

    const float* xr = x + (size_t)n*7;
    float px=xr[0], py=xr[1], pz=xr[2];
    float dx=xr[3], dy=xr[4], dz=xr[5];
    float appf = xr[6];
    float p0=(px+1.f)*0.5f, p1=(py+1.f)*0.5f, p2=(pz+1.f)*0.5f;

    float acc[HID];
#pragma unroll
    for (int o=0;o<HID;o++) acc[o]=0.f;

    const float2* tabs = reinterpret_cast<const float2*>(hash_tables);
    for (int l=0; l<NLEV; l++){
        float R = res.v[l];
        float ax=p0*R, ay=p1*R, az=p2*R;
        float fx=floorf(ax), fy=floorf(ay), fz=floorf(az);
        float rx=ax-fx, ry=ay-fy, rz=az-fz;
        uint32_t ix=(uint32_t)fx, iy=(uint32_t)fy, iz=(uint32_t)fz;
        const float2* tab = tabs + (size_t)l*TSIZE;
        uint32_t hx0=ix,               hx1=ix+1u;
        uint32_t hy0=iy*2654435761u,   hy1=(iy+1u)*2654435761u;
        uint32_t hz0=iz*805459861u,    hz1=(iz+1u)*805459861u;
        float wx0=1.f-rx, wx1=rx, wy0=1.f-ry, wy1=ry, wz0=1.f-rz, wz1=rz;
        float f0=0.f, f1=0.f;
#pragma unroll
        for (int c=0;c<8;c++){
            uint32_t hxx=(c&4)?hx1:hx0;
            uint32_t hyy=(c&2)?hy1:hy0;
            uint32_t hzz=(c&1)?hz1:hz0;
            uint32_t idx=(hxx^hyy^hzz)&(TSIZE-1u);
            float2 t = tab[idx];
            float w = ((c&4)?wx1:wx0)*((c&2)?wy1:wy0)*((c&1)?wz1:wz0);
            f0 = fmaf(w,t.x,f0);
            f1 = fmaf(w,t.y,f1);
        }
        AXPY64(acc, &s_ws0T[(2*l+0)*64], f0);
        AXPY64(acc, &s_ws0T[(2*l+1)*64], f1);
    }

    float pfv[24];
    plane_enc(planes, p0, p1, p2, pfv);
#pragma unroll
    for (int j=0;j<24;j++){
        AXPY64(acc, &s_ws0T[(32+j)*64], pfv[j]);
    }

    float h1[16];
#pragma unroll
    for (int j=0;j<16;j++) h1[j]=0.f;
#pragma unroll
    for (int k=0;k<HID;k++){
        float v = fmaxf(acc[k], 0.f);
        const float* wr = &s_ws1T[k*16];
#pragma unroll
        for (int j=0;j<16;j+=4){
            float4 w=ld4(wr+j);
            h1[j+0]=fmaf(w.x,v,h1[j+0]); h1[j+1]=fmaf(w.y,v,h1[j+1]);
            h1[j+2]=fmaf(w.z,v,h1[j+2]); h1[j+3]=fmaf(w.w,v,h1[j+3]);
        }
    }
    float sg = fminf(fmaxf(h1[0], -15.f), 15.f);
    float sigma = expf(sg);

#pragma unroll
    for (int o=0;o<HID;o++) acc[o]=0.f;

    float nrm = sqrtf(dx*dx+dy*dy+dz*dz);
    float sx=dx/nrm, sy=dy/nrm, sz=dz/nrm;
    float xx=sx*sx, yy=sy*sy, zz=sz*sz, xyv=sx*sy, yzv=sy*sz, xzv=sx*sz;
    float sh[16];
    sh[0]=0.28209479177387814f;
    sh[1]=-0.48860251190291987f*sy;
    sh[2]= 0.48860251190291987f*sz;
    sh[3]=-0.48860251190291987f*sx;
    sh[4]= 1.0925484305920792f*xyv;
    sh[5]=-1.0925484305920792f*yzv;
    sh[6]= 0.94617469575756f*zz-0.31539156525252005f;
    sh[7]=-1.0925484305920792f*xzv;
    sh[8]= 0.5462742152960396f*(xx-yy);
    sh[9]=-0.5900435899266435f*sy*(3.f*xx-yy);
    sh[10]=2.890611442640554f*xyv*sz;
    sh[11]=-0.4570457994644658f*sy*(4.f*zz-xx-yy);
    sh[12]=0.3731763325901154f*sz*(2.f*zz-3.f*xx-3.f*yy);
    sh[13]=-0.4570457994644658f*sx*(4.f*zz-xx-yy);
    sh[14]=1.445305721320277f*sz*(xx-yy);
    sh[15]=-0.5900435899266435f*sx*(xx-3.f*yy);
#pragma unroll
    for (int k=0;k<16;k++){
        AXPY64(acc, &s_wc0T[k*64], sh[k]);
    }
#pragma unroll
    for (int j=0;j<15;j++){
        AXPY64(acc, &s_wc0T[(16+j)*64], h1[1+j]);
    }
    {
        int ai = (int)appf;
        const float* ar = embed_a + (size_t)ai*48;
        for (int q=0;q<12;q++){
            float4 av = ld4(ar + q*4);
            const float* wc = &s_wc0T[(31+q*4)*64];
            AXPY64(acc, wc,       av.x);
            AXPY64(acc, wc+64,    av.y);
            AXPY64(acc, wc+128,   av.z);
            AXPY64(acc, wc+192,   av.w);
        }
    }
#pragma unroll
    for (int j=0;j<24;j++){
        AXPY64(acc, &s_wc0T[(79+j)*64], pfv[j]);
    }

    float acc2[HID];
#pragma unroll
    for (int o=0;o<HID;o++) acc2[o]=0.f;
#pragma unroll
    for (int k=0;k<HID;k++){
        float v = fmaxf(acc[k], 0.f);
        AXPY64(acc2, &s_wc1T[k*64], v);
    }

    float c0a=0.f, c1a=0.f, c2a=0.f;
#pragma unroll
    for (int k=0;k<HID;k++){
        float v = fmaxf(acc2[k], 0.f);
        float4 w = ld4(&s_wc2T[k*4]);
        c0a=fmaf(w.x,v,c0a); c1a=fmaf(w.y,v,c1a); c2a=fmaf(w.z,v,c2a);
    }
    float4 o4;
    o4.x = 1.f/(1.f+expf(-c0a));
    o4.y = 1.f/(1.f+expf(-c1a));
    o4.z = 1.f/(1.f+expf(-c2a));
    o4.w = sigma;
    *reinterpret_cast<float4*>(out + (size_t)n*4) = o4;
}

extern "C" void kernel_launch(void* const* d_in, const int* in_sizes, int n_in,
                              void* d_out, int out_size, void* d_ws, size_t ws_size,
                              hipStream_t stream) {
    const float* x        = (const float*)d_in[0];
    const float* ht       = (const float*)d_in[1];
    const float* planes   = (const float*)d_in[2];
    const float* embed_a  = (const float*)d_in[3];
    const float* w_sigma0 = (const float*)d_in[4];
    const float* w_sigma1 = (const float*)d_in[5];
    const float* w_color0 = (const float*)d_in[6];
    const float* w_color1 = (const float*)d_in[7];
    const float* w_color2 = (const float*)d_in[8];
    float* out = (float*)d_out;

    int npts = in_sizes[0] / 7;

    ResArr res;
    double b = exp((log(2048.0) - log(16.0)) / 15.0);
    for (int l=0; l<NLEV; l++)
        res.v[l] = (float)floor(16.0 * pow(b, (double)l));

    // ws layout (bytes)
    const size_t OFF_S0  = 0;
    const size_t OFF_S1  = OFF_S0 + 56*64*4;
    const size_t OFF_C2  = OFF_S1 + 64*16*4;
    const size_t OFF_AP  = OFF_C2 + 64*4*4;
    const size_t OFF_B0H = OFF_AP + 1024*64*4;
    const size_t OFF_B0L = OFF_B0H + 4096*2;
    const size_t OFF_B1H = OFF_B0L + 4096*2;
    const size_t OFF_B1L = OFF_B1H + 4096*2;
    const size_t OFF_SB0H= OFF_B1L + 4096*2;
    const size_t OFF_SB0L= OFF_SB0H + 4096*2;
    const size_t OFF_SB1H= OFF_SB0L + 4096*2;
    const size_t OFF_SB1L= OFF_SB1H + 1024*2;
    const size_t OFF_C2BH= OFF_SB1L + 1024*2;
    const size_t OFF_C2BL= OFF_C2BH + 1024*2;
    const size_t OFF_SMALL_END = OFF_C2BL + 1024*2;
    size_t feat_bytes = (size_t)npts * 16 * sizeof(uint32_t);
    size_t pp_bytes   = (size_t)npts * 16;
    size_t tb_bytes   = (size_t)16 * TSIZE * 4;      // 32MB

    const size_t OFF_PP   = OFF_SMALL_END;
    const size_t OFF_TB   = OFF_PP + pp_bytes;
    const size_t OFF_FEAT2= OFF_TB + tb_bytes;
    const size_t OFF_FEAT1= OFF_SMALL_END;

    bool full_path = (ws_size >= OFF_FEAT2 + feat_bytes);
    bool mid_path  = (ws_size >= OFF_FEAT1 + feat_bytes);

    if (full_path || mid_path) {
        char* base = (char*)d_ws;
        float* t_s0  = (float*)(base + OFF_S0);
        float* t_s1  = (float*)(base + OFF_S1);
        float* t_c2  = (float*)(base + OFF_C2);
        float* a_pre = (float*)(base + OFF_AP);
        short* c0Bhi = (short*)(base + OFF_B0H);
        short* c0Blo = (short*)(base + OFF_B0L);
        short* c1Bhi = (short*)(base + OFF_B1H);
        short* c1Blo = (short*)(base + OFF_B1L);
        short* s0Bhi = (short*)(base + OFF_SB0H);
        short* s0Blo = (short*)(base + OFF_SB0L);
        short* s1Bhi = (short*)(base + OFF_SB1H);
        short* s1Blo = (short*)(base + OFF_SB1L);
        short* c2Bhi = (short*)(base + OFF_C2BH);
        short* c2Blo = (short*)(base + OFF_C2BL);

        hipLaunchKernelGGL(nerf_ktrans, dim3(1), dim3(256), 0, stream,
                           w_sigma0, w_sigma1, w_color0, w_color1, w_color2,
                           t_s0, t_s1, t_c2, c0Bhi, c0Blo, c1Bhi, c1Blo,
                           s0Bhi, s0Blo, s1Bhi, s1Blo, c2Bhi, c2Blo);
        hipLaunchKernelGGL(nerf_kpre, dim3(1024), dim3(64), 0, stream,
                           embed_a, w_color0, a_pre);

        if (full_path) {
            float4*   pp      = (float4*)(base + OFF_PP);
            uint32_t* tabs_bf = (uint32_t*)(base + OFF_TB);
            uint32_t* feat    = (uint32_t*)(base + OFF_FEAT2);

            int total = 16 * (int)TSIZE;
            hipLaunchKernelGGL(nerf_krepack, dim3((total+255)/256), dim3(256), 0, stream,
                               (const float2*)ht, tabs_bf, total);
            hipLaunchKernelGGL(nerf_kprep, dim3((npts+255)/256), dim3(256), 0, stream,
                               x, pp, npts);

            int chunks = (npts + 2047) / 2048;
            hipLaunchKernelGGL(nerf_k0b, dim3(8*chunks), dim3(256), 0, stream,
                               pp, tabs_bf, feat, res, npts, 0);
            hipLaunchKernelGGL(nerf_k0b, dim3(8*chunks), dim3(256), 0, stream,
                               pp, tabs_bf, feat, res, npts, 8);

            int gm = (npts + 63) / 64;
            hipLaunchKernelGGL(nerf_k12m, dim3(gm), dim3(64), 0, stream,
                               x, planes, feat, a_pre,
                               s0Bhi, s0Blo, s1Bhi, s1Blo,
                               c0Bhi, c0Blo, c1Bhi, c1Blo, c2Bhi, c2Blo, out, npts);
        } else {
            uint32_t* feat = (uint32_t*)(base + OFF_FEAT1);
            int chunks = (npts + 511) / 512;
            hipLaunchKernelGGL(nerf_k0, dim3(8*chunks), dim3(256), 0, stream,
                               x, ht, feat, res, npts, 0);
            hipLaunchKernelGGL(nerf_k0, dim3(8*chunks), dim3(256), 0, stream,
                               x, ht, feat, res, npts, 8);
            int g = (npts + 255) / 256;
            hipLaunchKernelGGL(nerf_k1s, dim3(g), dim3(256), 0, stream,
                               x, planes, feat, t_s0, t_s1, npts);
            int gm = (npts + 63) / 64;
            hipLaunchKernelGGL(nerf_k2m, dim3(gm), dim3(64), 0, stream,
                               x, planes, feat, a_pre,
                               c0Bhi, c0Blo, c1Bhi, c1Blo, t_c2, out, npts);
        }
    } else {
        int grid = (npts + 255) / 256;
        hipLaunchKernelGGL(nerf_fwd, dim3(grid), dim3(256), 0, stream,
                           x, ht, planes, embed_a,
                           w_sigma0, w_sigma1, w_color0, w_color1, w_color2,
                           out, res, npts);
    }
}

// Round 14
// 675.704 us; speedup vs baseline: 1.0539x; 1.0150x over previous
//
#include <hip/hip_runtime.h>
#include <cmath>
#include <stdint.h>

#define NLEV  16
#define TSIZE (1u<<19)
#define PRES  512
#define PFD   8
#define HID   64
#define LDSH  72   // short stride per point row in MFMA LDS

struct ResArr { float v[NLEV]; };

typedef __attribute__((ext_vector_type(8))) short short8v;   // 8 bf16 (4 VGPRs)
typedef __attribute__((ext_vector_type(4))) float f32x4;

__device__ __forceinline__ float4 ld4(const float* p){ return *reinterpret_cast<const float4*>(p); }

__device__ __forceinline__ uint16_t f2bf(float f){
    uint32_t u = __float_as_uint(f);
    uint32_t r = (u + 0x7FFFu + ((u>>16)&1u)) >> 16;
    return (uint16_t)r;
}
__device__ __forceinline__ float bf2f(uint32_t h){ return __uint_as_float(h<<16); }
// Truncation split: hi = top 16 bits (1 op); lo = round(residual). Residual exact in fp32.
__device__ __forceinline__ uint16_t f2bf_hi(float f){ return (uint16_t)(__float_as_uint(f) >> 16); }
__device__ __forceinline__ float resid(float f, uint16_t hi){ return f - __uint_as_float((uint32_t)hi << 16); }

#define AXPY64(A, WPTR, V) do { const float* _w=(WPTR); const float _v=(V); \
  _Pragma("unroll") \
  for (int _o=0;_o<64;_o+=4){ float4 _w4=ld4(_w+_o); \
    A[_o+0]=fmaf(_w4.x,_v,A[_o+0]); A[_o+1]=fmaf(_w4.y,_v,A[_o+1]); \
    A[_o+2]=fmaf(_w4.z,_v,A[_o+2]); A[_o+3]=fmaf(_w4.w,_v,A[_o+3]); } } while(0)

__device__ __forceinline__ void plane_enc(const float* __restrict__ planes,
                                          float p0, float p1, float p2, float* pfv)
{
#pragma unroll
    for (int i=0;i<3;i++){
        float ua = (i==2? p1 : p0)*511.f;
        float va = (i==0? p1 : p2)*511.f;
        float uf=floorf(ua), vf=floorf(va);
        float wu=ua-uf, wv=va-vf;
        int u0=(int)uf; u0 = u0<0?0:(u0>510?510:u0);
        int v0=(int)vf; v0 = v0<0?0:(v0>510?510:v0);
        const float* pl = planes + ((size_t)i*PRES*PRES + (size_t)(u0*PRES+v0))*PFD;
        float4 a0=ld4(pl),              a1=ld4(pl+4);
        float4 b0=ld4(pl+PFD),          b1=ld4(pl+PFD+4);
        float4 c0=ld4(pl+PRES*PFD),     c1=ld4(pl+PRES*PFD+4);
        float4 d0=ld4(pl+PRES*PFD+PFD), d1=ld4(pl+PRES*PFD+PFD+4);
        float w00=(1.f-wu)*(1.f-wv), w01=(1.f-wu)*wv, w10=wu*(1.f-wv), w11=wu*wv;
        pfv[i*8+0]=a0.x*w00+b0.x*w01+c0.x*w10+d0.x*w11;
        pfv[i*8+1]=a0.y*w00+b0.y*w01+c0.y*w10+d0.y*w11;
        pfv[i*8+2]=a0.z*w00+b0.z*w01+c0.z*w10+d0.z*w11;
        pfv[i*8+3]=a0.w*w00+b0.w*w01+c0.w*w10+d0.w*w11;
        pfv[i*8+4]=a1.x*w00+b1.x*w01+c1.x*w10+d1.x*w11;
        pfv[i*8+5]=a1.y*w00+b1.y*w01+c1.y*w10+d1.y*w11;
        pfv[i*8+6]=a1.z*w00+b1.z*w01+c1.z*w10+d1.z*w11;
        pfv[i*8+7]=a1.w*w00+b1.w*w01+c1.w*w10+d1.w*w11;
    }
}

// ===================== krepack(+kprep): tables->bf16 AND pos prep, one launch ====
__global__ void nerf_krepack(const float2* __restrict__ tabs,
                             uint32_t* __restrict__ tabs_bf, int total,
                             const float* __restrict__ x, float4* __restrict__ pp, int npts)
{
    int nb_rep = (total + 255) / 256;
    if ((int)blockIdx.x < nb_rep){
        int i = blockIdx.x*256 + threadIdx.x;
        if (i < total){
            float2 t = tabs[i];
            tabs_bf[i] = (uint32_t)f2bf(t.x) | ((uint32_t)f2bf(t.y)<<16);
        }
    } else {
        int n = (blockIdx.x - nb_rep)*256 + threadIdx.x;
        if (n < npts){
            const float* xr = x + (size_t)n*7;
            pp[n] = make_float4((xr[0]+1.f)*0.5f, (xr[1]+1.f)*0.5f, (xr[2]+1.f)*0.5f, xr[6]);
        }
    }
}

// ===================== K0b: level-major hash gather, bf16 tables, 8 pts/thread ====
// (256,1): 256-VGPR cap so all 64 gathers + addresses stay in flight.
__global__ __launch_bounds__(256, 1)
void nerf_k0b(const float4* __restrict__ pp,
              const uint32_t* __restrict__ tabs_bf,
              uint32_t* __restrict__ feat,
              ResArr res, int npts, int lvl_base)
{
    int bid   = blockIdx.x;
    int level = lvl_base + (bid & 7);
    int chunk = bid >> 3;
    int base_n = chunk*2048 + threadIdx.x;
    float R = res.v[level];
    const uint32_t* tab = tabs_bf + (size_t)level*TSIZE;

    uint32_t g[8][8];
    float rx[8], ry[8], rz[8];
#pragma unroll
    for (int q=0;q<8;q++){
        int n = base_n + q*256;
        int nc = (n < npts) ? n : 0;
        float4 p = pp[nc];
        float ax=p.x*R, ay=p.y*R, az=p.z*R;
        float fx=floorf(ax), fy=floorf(ay), fz=floorf(az);
        rx[q]=ax-fx; ry[q]=ay-fy; rz[q]=az-fz;
        uint32_t ix=(uint32_t)fx, iy=(uint32_t)fy, iz=(uint32_t)fz;
        uint32_t hx0=ix,             hx1=ix+1u;
        uint32_t hy0=iy*2654435761u, hy1=(iy+1u)*2654435761u;
        uint32_t hz0=iz*805459861u,  hz1=(iz+1u)*805459861u;
#pragma unroll
        for (int c=0;c<8;c++){
            uint32_t idx = (((c&4)?hx1:hx0) ^ ((c&2)?hy1:hy0) ^ ((c&1)?hz1:hz0)) & (TSIZE-1u);
            g[q][c] = tab[idx];
        }
    }
#pragma unroll
    for (int q=0;q<8;q++){
        float wx0=1.f-rx[q], wy0=1.f-ry[q], wz0=1.f-rz[q];
        float f0=0.f, f1=0.f;
#pragma unroll
        for (int c=0;c<8;c++){
            float w = ((c&4)?rx[q]:wx0)*((c&2)?ry[q]:wy0)*((c&1)?rz[q]:wz0);
            f0 = fmaf(w, bf2f(g[q][c] & 0xFFFFu), f0);
            f1 = fmaf(w, bf2f(g[q][c] >> 16),     f1);
        }
        int n = base_n + q*256;
        if (n < npts) feat[(size_t)level*npts + n] = (uint32_t)f2bf(f0) | ((uint32_t)f2bf(f1)<<16);
    }
}

// ===================== K0: mid path (fp32 tables) =====================
__global__ __launch_bounds__(256, 2)
void nerf_k0(const float* __restrict__ x,
             const float* __restrict__ hash_tables,
             uint32_t* __restrict__ feat,
             ResArr res, int npts, int lvl_base)
{
    int bid   = blockIdx.x;
    int level = lvl_base + (bid & 7);
    int chunk = bid >> 3;
    int n0 = chunk*512 + threadIdx.x;
    int n1 = n0 + 256;
    float R = res.v[level];
    const float2* tab = reinterpret_cast<const float2*>(hash_tables) + (size_t)level*TSIZE;

    bool v0ok = (n0 < npts), v1ok = (n1 < npts);

    float p0a=0,p1a=0,p2a=0, p0b=0,p1b=0,p2b=0;
    if (v0ok){ const float* xr = x + (size_t)n0*7;
        p0a=(xr[0]+1.f)*0.5f; p1a=(xr[1]+1.f)*0.5f; p2a=(xr[2]+1.f)*0.5f; }
    if (v1ok){ const float* xr = x + (size_t)n1*7;
        p0b=(xr[0]+1.f)*0.5f; p1b=(xr[1]+1.f)*0.5f; p2b=(xr[2]+1.f)*0.5f; }

    float axa=p0a*R, aya=p1a*R, aza=p2a*R;
    float fxa=floorf(axa), fya=floorf(aya), fza=floorf(aza);
    float rxa=axa-fxa, rya=aya-fya, rza=aza-fza;
    uint32_t ixa=(uint32_t)fxa, iya=(uint32_t)fya, iza=(uint32_t)fza;
    uint32_t hx0a=ixa,             hx1a=ixa+1u;
    uint32_t hy0a=iya*2654435761u, hy1a=(iya+1u)*2654435761u;
    uint32_t hz0a=iza*805459861u,  hz1a=(iza+1u)*805459861u;

    float axb=p0b*R, ayb=p1b*R, azb=p2b*R;
    float fxb=floorf(axb), fyb=floorf(ayb), fzb=floorf(azb);
    float rxb=axb-fxb, ryb=ayb-fyb, rzb=azb-fzb;
    uint32_t ixb=(uint32_t)fxb, iyb=(uint32_t)fyb, izb=(uint32_t)fzb;
    uint32_t hx0b=ixb,             hx1b=ixb+1u;
    uint32_t hy0b=iyb*2654435761u, hy1b=(iyb+1u)*2654435761u;
    uint32_t hz0b=izb*805459861u,  hz1b=(izb+1u)*805459861u;

    float2 ta[8], tb[8];
#pragma unroll
    for (int c=0;c<8;c++){
        uint32_t idx = (((c&4)?hx1a:hx0a) ^ ((c&2)?hy1a:hy0a) ^ ((c&1)?hz1a:hz0a)) & (TSIZE-1u);
        ta[c] = tab[idx];
    }
#pragma unroll
    for (int c=0;c<8;c++){
        uint32_t idx = (((c&4)?hx1b:hx0b) ^ ((c&2)?hy1b:hy0b) ^ ((c&1)?hz1b:hz0b)) & (TSIZE-1u);
        tb[c] = tab[idx];
    }

    float wxa0=1.f-rxa, wya0=1.f-rya, wza0=1.f-rza;
    float f0a=0.f, f1a=0.f;
#pragma unroll
    for (int c=0;c<8;c++){
        float w = ((c&4)?rxa:wxa0)*((c&2)?rya:wya0)*((c&1)?rza:wza0);
        f0a = fmaf(w,ta[c].x,f0a); f1a = fmaf(w,ta[c].y,f1a);
    }
    float wxb0=1.f-rxb, wyb0=1.f-ryb, wzb0=1.f-rzb;
    float f0b=0.f, f1b=0.f;
#pragma unroll
    for (int c=0;c<8;c++){
        float w = ((c&4)?rxb:wxb0)*((c&2)?ryb:wyb0)*((c&1)?rzb:wzb0);
        f0b = fmaf(w,tb[c].x,f0b); f1b = fmaf(w,tb[c].y,f1b);
    }

    size_t base = (size_t)level*npts;
    if (v0ok) feat[base+n0] = (uint32_t)f2bf(f0a) | ((uint32_t)f2bf(f1a)<<16);
    if (v1ok) feat[base+n1] = (uint32_t)f2bf(f0b) | ((uint32_t)f2bf(f1b)<<16);
}

// ===================== ktrans(+kpre): weight prep + app_pre, one launch =====================
// block 0: fragment/transpose prep; blocks 1..1024: app_pre rows.
__global__ void nerf_ktrans(const float* __restrict__ w_sigma0,
                            const float* __restrict__ w_sigma1,
                            const float* __restrict__ w_color0,
                            const float* __restrict__ w_color1,
                            const float* __restrict__ w_color2,
                            float* __restrict__ t_s0, float* __restrict__ t_s1,
                            float* __restrict__ t_c2,
                            short* __restrict__ c0Bhi, short* __restrict__ c0Blo,
                            short* __restrict__ c1Bhi, short* __restrict__ c1Blo,
                            short* __restrict__ s0Bhi, short* __restrict__ s0Blo,
                            short* __restrict__ s1Bhi, short* __restrict__ s1Blo,
                            short* __restrict__ c2Bhi, short* __restrict__ c2Blo,
                            const float* __restrict__ embed_a,
                            float* __restrict__ app_pre)
{
    if (blockIdx.x > 0){
        // app_pre[a][o] for a = blockIdx.x-1 (64 threads used per row; launched 256)
        int a = blockIdx.x - 1;
        int o = threadIdx.x;
        if (o < 64){
            const float* er = embed_a + (size_t)a*48;
            const float* wr = w_color0 + (size_t)o*103 + 31;
            float s = 0.f;
#pragma unroll
            for (int j=0;j<48;j++) s = fmaf(er[j], wr[j], s);
            app_pre[(size_t)a*64 + o] = s;
        }
        return;
    }

    int tid = threadIdx.x;
    for (int i=tid;i<56*64; i+=256){ int k=i>>6,o=i&63; t_s0[i]=w_sigma0[o*56+k]; }
    for (int i=tid;i<64*16; i+=256){ int k=i>>4,j=i&15; t_s1[i]=w_sigma1[j*64+k]; }
    for (int i=tid;i<64*4;  i+=256){ int k=i>>2,o=i&3;  t_c2[i]=(o<3)?w_color2[o*64+k]:0.f; }

    for (int idx=tid; idx<4096; idx+=256){
        int nt = idx >> 10;
        int r1 = idx & 1023;
        int ks = r1 >> 9;
        int r2 = r1 & 511;
        int l  = r2 >> 3;
        int i  = r2 & 7;
        int out = nt*16 + (l & 15);
        int kk  = ks*32 + (l >> 4)*8 + i;
        float w0 = 0.f;
        if (kk < 31)       w0 = w_color0[out*103 + kk];
        else if (kk < 55)  w0 = w_color0[out*103 + kk + 48];
        uint16_t h0 = f2bf(w0);
        uint16_t l0 = f2bf(w0 - bf2f(h0));
        c0Bhi[idx] = (short)h0; c0Blo[idx] = (short)l0;
        float w1 = w_color1[out*64 + kk];
        uint16_t h1 = f2bf(w1);
        uint16_t l1 = f2bf(w1 - bf2f(h1));
        c1Bhi[idx] = (short)h1; c1Blo[idx] = (short)l1;
        float ws = (kk < 56) ? w_sigma0[out*56 + kk] : 0.f;
        uint16_t hs = f2bf(ws);
        uint16_t ls = f2bf(ws - bf2f(hs));
        s0Bhi[idx] = (short)hs; s0Blo[idx] = (short)ls;
    }
    for (int idx=tid; idx<1024; idx+=256){
        int ks = idx >> 9;
        int r2 = idx & 511;
        int l  = r2 >> 3;
        int i  = r2 & 7;
        int out = l & 15;
        int kk  = ks*32 + (l >> 4)*8 + i;
        float w = w_sigma1[out*64 + kk];
        uint16_t h = f2bf(w);
        s1Bhi[idx] = (short)h; s1Blo[idx] = (short)f2bf(w - bf2f(h));
        float wc = (out < 3) ? w_color2[out*64 + kk] : 0.f;
        uint16_t hc2 = f2bf(wc);
        c2Bhi[idx] = (short)hc2; c2Blo[idx] = (short)f2bf(wc - bf2f(hc2));
    }
}

// ===================== K1s: mid-path sigma MLP (VALU) =====================
__global__ __launch_bounds__(256, 2)
void nerf_k1s(const float* __restrict__ x,
              const float* __restrict__ planes,
              uint32_t* __restrict__ feat,
              const float* __restrict__ wT_s0,
              const float* __restrict__ wT_s1,
              int npts)
{
    int n = blockIdx.x*256 + threadIdx.x;
    if (n >= npts) return;

    uint32_t fl[NLEV];
#pragma unroll
    for (int l=0;l<NLEV;l++) fl[l] = feat[(size_t)l*npts + n];

    float acc[HID];
#pragma unroll
    for (int o=0;o<HID;o++) acc[o]=0.f;

#pragma unroll
    for (int l=0;l<NLEV;l++){
        float f0 = bf2f(fl[l] & 0xFFFFu);
        float f1 = bf2f(fl[l] >> 16);
        AXPY64(acc, &wT_s0[(2*l+0)*64], f0);
        AXPY64(acc, &wT_s0[(2*l+1)*64], f1);
    }

    const float* xr = x + (size_t)n*7;
    float p0=(xr[0]+1.f)*0.5f, p1=(xr[1]+1.f)*0.5f, p2=(xr[2]+1.f)*0.5f;
    float pfv[24];
    plane_enc(planes, p0, p1, p2, pfv);
#pragma unroll
    for (int j=0;j<24;j++){
        AXPY64(acc, &wT_s0[(32+j)*64], pfv[j]);
    }

    float h1[16];
#pragma unroll
    for (int j=0;j<16;j++) h1[j]=0.f;
#pragma unroll
    for (int k=0;k<HID;k++){
        float v = fmaxf(acc[k], 0.f);
        const float* wr = &wT_s1[k*16];
#pragma unroll
        for (int j=0;j<16;j+=4){
            float4 w=ld4(wr+j);
            h1[j+0]=fmaf(w.x,v,h1[j+0]); h1[j+1]=fmaf(w.y,v,h1[j+1]);
            h1[j+2]=fmaf(w.z,v,h1[j+2]); h1[j+3]=fmaf(w.w,v,h1[j+3]);
        }
    }
    float sg = fminf(fmaxf(h1[0], -15.f), 15.f);
    float sigma = expf(sg);

#pragma unroll
    for (int l=0;l<15;l++) feat[(size_t)l*npts + n] = __float_as_uint(h1[l+1]);
    feat[(size_t)15*npts + n] = __float_as_uint(sigma);
}

// ===================== K2m: mid-path color MLP (MFMA, R8-verified) =====================
__global__ __launch_bounds__(64, 1)
void nerf_k2m(const float* __restrict__ x,
              const float* __restrict__ planes,
              const uint32_t* __restrict__ feat,
              const float* __restrict__ app_pre,
              const short* __restrict__ c0Bhi, const short* __restrict__ c0Blo,
              const short* __restrict__ c1Bhi, const short* __restrict__ c1Blo,
              const float* __restrict__ t_c2,
              float* __restrict__ out, int npts)
{
    __shared__ uint16_t ldsA[2*64*LDSH];
    __shared__ int      lds_ai[64];

    const int l = threadIdx.x;
    int n = blockIdx.x*64 + l;
    bool ok = (n < npts);
    int nc = ok ? n : (npts-1);
    const float* xr = x + (size_t)nc*7;

    {
        float av[55];
        float dx=xr[3], dy=xr[4], dz=xr[5];
        float nrm = sqrtf(dx*dx+dy*dy+dz*dz);
        float sx=dx/nrm, sy=dy/nrm, sz=dz/nrm;
        float xx=sx*sx, yy=sy*sy, zz=sz*sz, xyv=sx*sy, yzv=sy*sz, xzv=sx*sz;
        av[0]=0.28209479177387814f;
        av[1]=-0.48860251190291987f*sy;
        av[2]= 0.48860251190291987f*sz;
        av[3]=-0.48860251190291987f*sx;
        av[4]= 1.0925484305920792f*xyv;
        av[5]=-1.0925484305920792f*yzv;
        av[6]= 0.94617469575756f*zz-0.31539156525252005f;
        av[7]=-1.0925484305920792f*xzv;
        av[8]= 0.5462742152960396f*(xx-yy);
        av[9]=-0.5900435899266435f*sy*(3.f*xx-yy);
        av[10]=2.890611442640554f*xyv*sz;
        av[11]=-0.4570457994644658f*sy*(4.f*zz-xx-yy);
        av[12]=0.3731763325901154f*sz*(2.f*zz-3.f*xx-3.f*yy);
        av[13]=-0.4570457994644658f*sx*(4.f*zz-xx-yy);
        av[14]=1.445305721320277f*sz*(xx-yy);
        av[15]=-0.5900435899266435f*sx*(xx-3.f*yy);
#pragma unroll
        for (int j=0;j<15;j++) av[16+j] = __uint_as_float(feat[(size_t)j*npts + nc]);
        float pfv[24];
        plane_enc(planes, (xr[0]+1.f)*0.5f, (xr[1]+1.f)*0.5f, (xr[2]+1.f)*0.5f, pfv);
#pragma unroll
        for (int j=0;j<24;j++) av[31+j] = pfv[j];

        uint16_t* rh = &ldsA[l*LDSH];
        uint16_t* rl = &ldsA[64*LDSH + l*LDSH];
#pragma unroll
        for (int kk=0; kk<64; kk++){
            float a = (kk<55) ? av[kk] : 0.f;
            uint16_t hi = f2bf(a);
            uint16_t lo = f2bf(a - bf2f(hi));
            rh[kk] = hi; rl[kk] = lo;
        }
        lds_ai[l] = (int)xr[6];
    }
    __syncthreads();

    f32x4 acc[4][4];
    {
        const int lq = l >> 4, lr = l & 15;
#pragma unroll
        for (int mt=0; mt<4; mt++){
#pragma unroll
            for (int r=0; r<4; r++){
                int ai = lds_ai[mt*16 + lq*4 + r];
                const float* ap = app_pre + (size_t)ai*64 + lr;
#pragma unroll
                for (int nt=0; nt<4; nt++)
                    acc[mt][nt][r] = ap[nt*16];
            }
        }
    }
    {
        const int lq = l >> 4, lr = l & 15;
#pragma unroll
        for (int ks=0; ks<2; ks++){
            short8v ah[4], al[4];
#pragma unroll
            for (int mt=0; mt<4; mt++){
                const uint16_t* ph = &ldsA[(mt*16+lr)*LDSH + ks*32 + lq*8];
                ah[mt] = *reinterpret_cast<const short8v*>(ph);
                al[mt] = *reinterpret_cast<const short8v*>(ph + 64*LDSH);
            }
#pragma unroll
            for (int nt=0; nt<4; nt++){
                short8v bh = *reinterpret_cast<const short8v*>(&c0Bhi[(nt*2+ks)*512 + l*8]);
                short8v bl = *reinterpret_cast<const short8v*>(&c0Blo[(nt*2+ks)*512 + l*8]);
#pragma unroll
                for (int mt=0; mt<4; mt++){
                    acc[mt][nt] = __builtin_amdgcn_mfma_f32_16x16x32_bf16(ah[mt], bh, acc[mt][nt], 0,0,0);
                    acc[mt][nt] = __builtin_amdgcn_mfma_f32_16x16x32_bf16(ah[mt], bl, acc[mt][nt], 0,0,0);
                    acc[mt][nt] = __builtin_amdgcn_mfma_f32_16x16x32_bf16(al[mt], bh, acc[mt][nt], 0,0,0);
                }
            }
        }
    }
    __syncthreads();

    {
        const int lq = l >> 4, lr = l & 15;
#pragma unroll
        for (int mt=0; mt<4; mt++){
#pragma unroll
            for (int nt=0; nt<4; nt++){
#pragma unroll
                for (int r=0; r<4; r++){
                    float v = fmaxf(acc[mt][nt][r], 0.f);
                    uint16_t hi = f2bf(v);
                    uint16_t lo = f2bf(v - bf2f(hi));
                    int pt = mt*16 + lq*4 + r;
                    int ch = nt*16 + lr;
                    ldsA[pt*LDSH + ch] = hi;
                    ldsA[64*LDSH + pt*LDSH + ch] = lo;
                }
            }
        }
    }
    __syncthreads();

    {
        const int lq = l >> 4, lr = l & 15;
#pragma unroll
        for (int mt=0; mt<4; mt++)
#pragma unroll
            for (int nt=0; nt<4; nt++){
                acc[mt][nt][0]=0.f; acc[mt][nt][1]=0.f; acc[mt][nt][2]=0.f; acc[mt][nt][3]=0.f;
            }
#pragma unroll
        for (int ks=0; ks<2; ks++){
            short8v ah[4], al[4];
#pragma unroll
            for (int mt=0; mt<4; mt++){
                const uint16_t* ph = &ldsA[(mt*16+lr)*LDSH + ks*32 + lq*8];
                ah[mt] = *reinterpret_cast<const short8v*>(ph);
                al[mt] = *reinterpret_cast<const short8v*>(ph + 64*LDSH);
            }
#pragma unroll
            for (int nt=0; nt<4; nt++){
                short8v bh = *reinterpret_cast<const short8v*>(&c1Bhi[(nt*2+ks)*512 + l*8]);
                short8v bl = *reinterpret_cast<const short8v*>(&c1Blo[(nt*2+ks)*512 + l*8]);
#pragma unroll
                for (int mt=0; mt<4; mt++){
                    acc[mt][nt] = __builtin_amdgcn_mfma_f32_16x16x32_bf16(ah[mt], bh, acc[mt][nt], 0,0,0);
                    acc[mt][nt] = __builtin_amdgcn_mfma_f32_16x16x32_bf16(ah[mt], bl, acc[mt][nt], 0,0,0);
                    acc[mt][nt] = __builtin_amdgcn_mfma_f32_16x16x32_bf16(al[mt], bh, acc[mt][nt], 0,0,0);
                }
            }
        }
    }
    __syncthreads();

    {
        float* ldsF = reinterpret_cast<float*>(ldsA);
        const int lq = l >> 4, lr = l & 15;
#pragma unroll
        for (int mt=0; mt<4; mt++){
#pragma unroll
            for (int nt=0; nt<4; nt++){
#pragma unroll
                for (int r=0; r<4; r++){
                    int pt = mt*16 + lq*4 + r;
                    int ch = nt*16 + lr;
                    ldsF[pt*66 + ch] = fmaxf(acc[mt][nt][r], 0.f);
                }
            }
        }
        __syncthreads();

        float c0=0.f, c1=0.f, c2=0.f;
        const float* row = &ldsF[l*66];
#pragma unroll
        for (int ch=0; ch<64; ch++){
            float v = row[ch];
            float4 w = ld4(&t_c2[ch*4]);
            c0 = fmaf(w.x, v, c0);
            c1 = fmaf(w.y, v, c1);
            c2 = fmaf(w.z, v, c2);
        }
        if (ok){
            float sigma = __uint_as_float(feat[(size_t)15*npts + n]);
            float4 o4;
            o4.x = 1.f/(1.f+expf(-c0));
            o4.y = 1.f/(1.f+expf(-c1));
            o4.z = 1.f/(1.f+expf(-c2));
            o4.w = sigma;
            *reinterpret_cast<float4*>(out + (size_t)n*4) = o4;
        }
    }
}

// ===================== K12m v4: FUSED sigma+color MLP via MFMA, trunc hi-split ====
__global__ __launch_bounds__(64, 1)
void nerf_k12m(const float* __restrict__ x,
               const float* __restrict__ planes,
               const uint32_t* __restrict__ feat,
               const float* __restrict__ app_pre,
               const short* __restrict__ s0Bhi, const short* __restrict__ s0Blo,
               const short* __restrict__ s1Bhi, const short* __restrict__ s1Blo,
               const short* __restrict__ c0Bhi, const short* __restrict__ c0Blo,
               const short* __restrict__ c1Bhi, const short* __restrict__ c1Blo,
               const short* __restrict__ c2Bhi, const short* __restrict__ c2Blo,
               float* __restrict__ out, int npts)
{
    __shared__ uint16_t ldsA[64*LDSH];   // hi plane
    __shared__ uint16_t ldsB[64*LDSH];   // lo plane
    __shared__ float    obuf[64*4];
    __shared__ float    sig[64];
    __shared__ int      lds_ai[64];

    const int l = threadIdx.x;
    const int lq = l >> 4, lr = l & 15;
    int n = blockIdx.x*64 + l;
    bool ok = (n < npts);
    int nc = ok ? n : (npts-1);
    const float* xr = x + (size_t)nc*7;

    float pfv[24];
    float sh[16];
    {
        float dx=xr[3], dy=xr[4], dz=xr[5];
        float nrm = sqrtf(dx*dx+dy*dy+dz*dz);
        float sx=dx/nrm, sy=dy/nrm, sz=dz/nrm;
        float xx=sx*sx, yy=sy*sy, zz=sz*sz, xyv=sx*sy, yzv=sy*sz, xzv=sx*sz;
        sh[0]=0.28209479177387814f;
        sh[1]=-0.48860251190291987f*sy;
        sh[2]= 0.48860251190291987f*sz;
        sh[3]=-0.48860251190291987f*sx;
        sh[4]= 1.0925484305920792f*xyv;
        sh[5]=-1.0925484305920792f*yzv;
        sh[6]= 0.94617469575756f*zz-0.31539156525252005f;
        sh[7]=-1.0925484305920792f*xzv;
        sh[8]= 0.5462742152960396f*(xx-yy);
        sh[9]=-0.5900435899266435f*sy*(3.f*xx-yy);
        sh[10]=2.890611442640554f*xyv*sz;
        sh[11]=-0.4570457994644658f*sy*(4.f*zz-xx-yy);
        sh[12]=0.3731763325901154f*sz*(2.f*zz-3.f*xx-3.f*yy);
        sh[13]=-0.4570457994644658f*sx*(4.f*zz-xx-yy);
        sh[14]=1.445305721320277f*sz*(xx-yy);
        sh[15]=-0.5900435899266435f*sx*(xx-3.f*yy);
        plane_enc(planes, (xr[0]+1.f)*0.5f, (xr[1]+1.f)*0.5f, (xr[2]+1.f)*0.5f, pfv);
        lds_ai[l] = (int)xr[6];
    }

    // ---- phase 1: sigma0 A-tile: hash u32-exact (cols 0-31, lo=0), planes trunc-split ----
    {
        uint16_t* rh = &ldsA[l*LDSH];
        uint16_t* rl = &ldsB[l*LDSH];
#pragma unroll
        for (int lv=0; lv<16; lv++){
            *reinterpret_cast<uint32_t*>(&rh[2*lv]) = feat[(size_t)lv*npts + nc];
            *reinterpret_cast<uint32_t*>(&rl[2*lv]) = 0u;
        }
#pragma unroll
        for (int j=0;j<24;j++){
            float a = pfv[j];
            uint16_t hi = f2bf_hi(a);
            rh[32+j] = hi;
            rl[32+j] = f2bf(resid(a, hi));
        }
#pragma unroll
        for (int j=56;j<64;j++){ rh[j]=0; rl[j]=0; }
    }
    __syncthreads();

    // ---- phase 2: sigma0 MFMA (3-term; ks=0 A-lo==0 -> skip al term, exact) ----
    f32x4 acc[4][4];
#pragma unroll
    for (int mt=0; mt<4; mt++)
#pragma unroll
        for (int nt=0; nt<4; nt++){
            acc[mt][nt][0]=0.f; acc[mt][nt][1]=0.f; acc[mt][nt][2]=0.f; acc[mt][nt][3]=0.f;
        }
#pragma unroll
    for (int ks=0; ks<2; ks++){
        short8v ah[4], al[4];
#pragma unroll
        for (int mt=0; mt<4; mt++){
            ah[mt] = *reinterpret_cast<const short8v*>(&ldsA[(mt*16+lr)*LDSH + ks*32 + lq*8]);
            al[mt] = *reinterpret_cast<const short8v*>(&ldsB[(mt*16+lr)*LDSH + ks*32 + lq*8]);
        }
#pragma unroll
        for (int nt=0; nt<4; nt++){
            short8v bh = *reinterpret_cast<const short8v*>(&s0Bhi[(nt*2+ks)*512 + l*8]);
            short8v bl = *reinterpret_cast<const short8v*>(&s0Blo[(nt*2+ks)*512 + l*8]);
#pragma unroll
            for (int mt=0; mt<4; mt++){
                acc[mt][nt] = __builtin_amdgcn_mfma_f32_16x16x32_bf16(ah[mt], bh, acc[mt][nt], 0,0,0);
                acc[mt][nt] = __builtin_amdgcn_mfma_f32_16x16x32_bf16(ah[mt], bl, acc[mt][nt], 0,0,0);
                if (ks==1)
                    acc[mt][nt] = __builtin_amdgcn_mfma_f32_16x16x32_bf16(al[mt], bh, acc[mt][nt], 0,0,0);
            }
        }
    }
    __syncthreads();

    // ---- phase 3: relu(h0) repack trunc-split ----
#pragma unroll
    for (int mt=0; mt<4; mt++){
#pragma unroll
        for (int nt=0; nt<4; nt++){
#pragma unroll
            for (int r=0; r<4; r++){
                float v = fmaxf(acc[mt][nt][r], 0.f);
                uint16_t hi = f2bf_hi(v);
                int pt = mt*16 + lq*4 + r;
                int ch = nt*16 + lr;
                ldsA[pt*LDSH + ch] = hi;
                ldsB[pt*LDSH + ch] = f2bf(resid(v, hi));
            }
        }
    }
    __syncthreads();

    // ---- phase 4: sigma1 MFMA (3-term, out=16) ----
    f32x4 acc2[4];
#pragma unroll
    for (int mt=0; mt<4; mt++){ acc2[mt][0]=0.f; acc2[mt][1]=0.f; acc2[mt][2]=0.f; acc2[mt][3]=0.f; }
#pragma unroll
    for (int ks=0; ks<2; ks++){
        short8v bh = *reinterpret_cast<const short8v*>(&s1Bhi[ks*512 + l*8]);
        short8v bl = *reinterpret_cast<const short8v*>(&s1Blo[ks*512 + l*8]);
#pragma unroll
        for (int mt=0; mt<4; mt++){
            short8v ah = *reinterpret_cast<const short8v*>(&ldsA[(mt*16+lr)*LDSH + ks*32 + lq*8]);
            short8v al = *reinterpret_cast<const short8v*>(&ldsB[(mt*16+lr)*LDSH + ks*32 + lq*8]);
            acc2[mt] = __builtin_amdgcn_mfma_f32_16x16x32_bf16(ah, bh, acc2[mt], 0,0,0);
            acc2[mt] = __builtin_amdgcn_mfma_f32_16x16x32_bf16(ah, bl, acc2[mt], 0,0,0);
            acc2[mt] = __builtin_amdgcn_mfma_f32_16x16x32_bf16(al, bh, acc2[mt], 0,0,0);
        }
    }
    __syncthreads();

    // ---- phase 5: build color0 A-tile trunc-split: sh 0-15, geo 16-30 (D-scatter), pf 31-54 ----
    {
        uint16_t* rh = &ldsA[l*LDSH];
        uint16_t* rl = &ldsB[l*LDSH];
#pragma unroll
        for (int j=0;j<16;j++){
            float a = sh[j];
            uint16_t hi = f2bf_hi(a);
            rh[j] = hi; rl[j] = f2bf(resid(a, hi));
        }
#pragma unroll
        for (int j=0;j<24;j++){
            float a = pfv[j];
            uint16_t hi = f2bf_hi(a);
            rh[31+j] = hi; rl[31+j] = f2bf(resid(a, hi));
        }
#pragma unroll
        for (int j=55;j<64;j++){ rh[j]=0; rl[j]=0; }

        int ch = lr;
#pragma unroll
        for (int mt=0; mt<4; mt++){
#pragma unroll
            for (int r=0; r<4; r++){
                int pt = mt*16 + lq*4 + r;
                float v = acc2[mt][r];
                if (ch == 0){
                    sig[pt] = v;
                } else {
                    uint16_t hi = f2bf_hi(v);
                    ldsA[pt*LDSH + 16 + (ch-1)] = hi;
                    ldsB[pt*LDSH + 16 + (ch-1)] = f2bf(resid(v, hi));
                }
            }
        }
    }
    __syncthreads();

    // ---- phase 6: color0 MFMA (3-term, app_pre C-init) ----
#pragma unroll
    for (int mt=0; mt<4; mt++){
#pragma unroll
        for (int r=0; r<4; r++){
            int ai = lds_ai[mt*16 + lq*4 + r];
            const float* ap = app_pre + (size_t)ai*64 + lr;
#pragma unroll
            for (int nt=0; nt<4; nt++)
                acc[mt][nt][r] = ap[nt*16];
        }
    }
#pragma unroll
    for (int ks=0; ks<2; ks++){
        short8v ah[4], al[4];
#pragma unroll
        for (int mt=0; mt<4; mt++){
            ah[mt] = *reinterpret_cast<const short8v*>(&ldsA[(mt*16+lr)*LDSH + ks*32 + lq*8]);
            al[mt] = *reinterpret_cast<const short8v*>(&ldsB[(mt*16+lr)*LDSH + ks*32 + lq*8]);
        }
#pragma unroll
        for (int nt=0; nt<4; nt++){
            short8v bh = *reinterpret_cast<const short8v*>(&c0Bhi[(nt*2+ks)*512 + l*8]);
            short8v bl = *reinterpret_cast<const short8v*>(&c0Blo[(nt*2+ks)*512 + l*8]);
#pragma unroll
            for (int mt=0; mt<4; mt++){
                acc[mt][nt] = __builtin_amdgcn_mfma_f32_16x16x32_bf16(ah[mt], bh, acc[mt][nt], 0,0,0);
                acc[mt][nt] = __builtin_amdgcn_mfma_f32_16x16x32_bf16(ah[mt], bl, acc[mt][nt], 0,0,0);
                acc[mt][nt] = __builtin_amdgcn_mfma_f32_16x16x32_bf16(al[mt], bh, acc[mt][nt], 0,0,0);
            }
        }
    }
    __syncthreads();

    // ---- phase 7: relu repack trunc-split; color1 MFMA (3-term) ----
#pragma unroll
    for (int mt=0; mt<4; mt++){
#pragma unroll
        for (int nt=0; nt<4; nt++){
#pragma unroll
            for (int r=0; r<4; r++){
                float v = fmaxf(acc[mt][nt][r], 0.f);
                uint16_t hi = f2bf_hi(v);
                int pt = mt*16 + lq*4 + r;
                int ch = nt*16 + lr;
                ldsA[pt*LDSH + ch] = hi;
                ldsB[pt*LDSH + ch] = f2bf(resid(v, hi));
            }
        }
    }
    __syncthreads();

#pragma unroll
    for (int mt=0; mt<4; mt++)
#pragma unroll
        for (int nt=0; nt<4; nt++){
            acc[mt][nt][0]=0.f; acc[mt][nt][1]=0.f; acc[mt][nt][2]=0.f; acc[mt][nt][3]=0.f;
        }
#pragma unroll
    for (int ks=0; ks<2; ks++){
        short8v ah[4], al[4];
#pragma unroll
        for (int mt=0; mt<4; mt++){
            ah[mt] = *reinterpret_cast<const short8v*>(&ldsA[(mt*16+lr)*LDSH + ks*32 + lq*8]);
            al[mt] = *reinterpret_cast<const short8v*>(&ldsB[(mt*16+lr)*LDSH + ks*32 + lq*8]);
        }
#pragma unroll
        for (int nt=0; nt<4; nt++){
            short8v bh = *reinterpret_cast<const short8v*>(&c1Bhi[(nt*2+ks)*512 + l*8]);
            short8v bl = *reinterpret_cast<const short8v*>(&c1Blo[(nt*2+ks)*512 + l*8]);
#pragma unroll
            for (int mt=0; mt<4; mt++){
                acc[mt][nt] = __builtin_amdgcn_mfma_f32_16x16x32_bf16(ah[mt], bh, acc[mt][nt], 0,0,0);
                acc[mt][nt] = __builtin_amdgcn_mfma_f32_16x16x32_bf16(ah[mt], bl, acc[mt][nt], 0,0,0);
                acc[mt][nt] = __builtin_amdgcn_mfma_f32_16x16x32_bf16(al[mt], bh, acc[mt][nt], 0,0,0);
            }
        }
    }
    __syncthreads();

    // ---- phase 8: relu repack trunc-split; color2 MFMA (3-term); scatter; store ----
#pragma unroll
    for (int mt=0; mt<4; mt++){
#pragma unroll
        for (int nt=0; nt<4; nt++){
#pragma unroll
            for (int r=0; r<4; r++){
                float v = fmaxf(acc[mt][nt][r], 0.f);
                uint16_t hi = f2bf_hi(v);
                int pt = mt*16 + lq*4 + r;
                int ch = nt*16 + lr;
                ldsA[pt*LDSH + ch] = hi;
                ldsB[pt*LDSH + ch] = f2bf(resid(v, hi));
            }
        }
    }
    __syncthreads();

    f32x4 acc3[4];
#pragma unroll
    for (int mt=0; mt<4; mt++){ acc3[mt][0]=0.f; acc3[mt][1]=0.f; acc3[mt][2]=0.f; acc3[mt][3]=0.f; }
#pragma unroll
    for (int ks=0; ks<2; ks++){
        short8v bh = *reinterpret_cast<const short8v*>(&c2Bhi[ks*512 + l*8]);
        short8v bl = *reinterpret_cast<const short8v*>(&c2Blo[ks*512 + l*8]);
#pragma unroll
        for (int mt=0; mt<4; mt++){
            short8v ah = *reinterpret_cast<const short8v*>(&ldsA[(mt*16+lr)*LDSH + ks*32 + lq*8]);
            short8v al = *reinterpret_cast<const short8v*>(&ldsB[(mt*16+lr)*LDSH + ks*32 + lq*8]);
            acc3[mt] = __builtin_amdgcn_mfma_f32_16x16x32_bf16(ah, bh, acc3[mt], 0,0,0);
            acc3[mt] = __builtin_amdgcn_mfma_f32_16x16x32_bf16(ah, bl, acc3[mt], 0,0,0);
            acc3[mt] = __builtin_amdgcn_mfma_f32_16x16x32_bf16(al, bh, acc3[mt], 0,0,0);
        }
    }
    if (lr < 3){
#pragma unroll
        for (int mt=0; mt<4; mt++){
#pragma unroll
            for (int r=0; r<4; r++){
                obuf[(mt*16 + lq*4 + r)*4 + lr] = acc3[mt][r];
            }
        }
    }
    __syncthreads();

    if (ok){
        float sg = fminf(fmaxf(sig[l], -15.f), 15.f);
        float4 o4;
        o4.x = 1.f/(1.f+expf(-obuf[l*4+0]));
        o4.y = 1.f/(1.f+expf(-obuf[l*4+1]));
        o4.z = 1.f/(1.f+expf(-obuf[l*4+2]));
        o4.w = expf(sg);
        *reinterpret_cast<float4*>(out + (size_t)n*4) = o4;
    }
}

// ===================== fallback single kernel =====================
__global__ __launch_bounds__(256, 1)
void nerf_fwd(const float* __restrict__ x,
              const float* __restrict__ hash_tables,
              const float* __restrict__ planes,
              const float* __restrict__ embed_a,
              const float* __restrict__ w_sigma0,
              const float* __restrict__ w_sigma1,
              const float* __restrict__ w_color0,
              const float* __restrict__ w_color1,
              const float* __restrict__ w_color2,
              float* __restrict__ out,
              ResArr res, int npts)
{
    __shared__ float s_ws0T[56*64];
    __shared__ float s_ws1T[64*16];
    __shared__ float s_wc0T[103*64];
    __shared__ float s_wc1T[64*64];
    __shared__ float s_wc2T[64*4];

    for (int i = threadIdx.x; i < 56*64;  i += 256){ int k=i>>6, o=i&63; s_ws0T[i] = w_sigma0[o*56+k]; }
    for (int i = threadIdx.x; i < 64*16;  i += 256){ int k=i>>4, j=i&15; s_ws1T[i] = w_sigma1[j*64+k]; }
    for (int i = threadIdx.x; i < 103*64; i += 256){ int k=i>>6, o=i&63; s_wc0T[i] = w_color0[o*103+k]; }
    for (int i = threadIdx.x; i < 64*64;  i += 256){ int k=i>>6, o=i&63; s_wc1T[i] = w_color1[o*64+k]; }
    for (int i = threadIdx.x; i < 64*4;   i += 256){ int k=i>>2, o=i&3;  s_wc2T[i] = (o<3)? w_color2[o*64+k] : 0.f; }
    __syncthreads();

    int n = blockIdx.x*256 + threadIdx.x;
    if (n >= npts) return;

    const float* xr = x + (size_t)n*7;
    float px=xr[0], py=xr[1], pz=xr[2];
    float dx=xr[3], dy=xr[4], dz=xr[5];
    float appf = xr[6];
    float p0=(px+1.f)*0.5f, p1=(py+1.f)*0.5f, p2=(pz+1.f)*0.5f;

    float acc[HID];
#pragma unroll
    for (int o=0;o<HID;o++) acc[o]=0.f;

    const float2* tabs = reinterpret_cast<const float2*>(hash_tables);
    for (int l=0; l<NLEV; l++){
        float R = res.v[l];
        float ax=p0*R, ay=p1*R, az=p2*R;
        float fx=floorf(ax), fy=floorf(ay), fz=floorf(az);
        float rx=ax-fx, ry=ay-fy, rz=az-fz;
        uint32_t ix=(uint32_t)fx, iy=(uint32_t)fy, iz=(uint32_t)fz;
        const float2* tab = tabs + (size_t)l*TSIZE;
        uint32_t hx0=ix,               hx1=ix+1u;
        uint32_t hy0=iy*2654435761u,   hy1=(iy+1u)*2654435761u;
        uint32_t hz0=iz*805459861u,    hz1=(iz+1u)*805459861u;
        float wx0=1.f-rx, wx1=rx, wy0=1.f-ry, wy1=ry, wz0=1.f-rz, wz1=rz;
        float f0=0.f, f1=0.f;
#pragma unroll
        for (int c=0;c<8;c++){
            uint32_t hxx=(c&4)?hx1:hx0;
            uint32_t hyy=(c&2)?hy1:hy0;
            uint32_t hzz=(c&1)?hz1:hz0;
            uint32_t idx=(hxx^hyy^hzz)&(TSIZE-1u);
            float2 t = tab[idx];
            float w = ((c&4)?wx1:wx0)*((c&2)?wy1:wy0)*((c&1)?wz1:wz0);
            f0 = fmaf(w,t.x,f0);
            f1 = fmaf(w,t.y,f1);
        }
        AXPY64(acc, &s_ws0T[(2*l+0)*64], f0);
        AXPY64(acc, &s_ws0T[(2*l+1)*64], f1);
    }

    float pfv[24];
    plane_enc(planes, p0, p1, p2, pfv);
#pragma unroll
    for (int j=0;j<24;j++){
        AXPY64(acc, &s_ws0T[(32+j)*64], pfv[j]);
    }

    float h1[16];
#pragma unroll
    for (int j=0;j<16;j++) h1[j]=0.f;
#pragma unroll
    for (int k=0;k<HID;k++){
        float v = fmaxf(acc[k], 0.f);
        const float* wr = &s_ws1T[k*16];
#pragma unroll
        for (int j=0;j<16;j+=4){
            float4 w=ld4(wr+j);
            h1[j+0]=fmaf(w.x,v,h1[j+0]); h1[j+1]=fmaf(w.y,v,h1[j+1]);
            h1[j+2]=fmaf(w.z,v,h1[j+2]); h1[j+3]=fmaf(w.w,v,h1[j+3]);
        }
    }
    float sg = fminf(fmaxf(h1[0], -15.f), 15.f);
    float sigma = expf(sg);

#pragma unroll
    for (int o=0;o<HID;o++) acc[o]=0.f;

    float nrm = sqrtf(dx*dx+dy*dy+dz*dz);
    float sx=dx/nrm, sy=dy/nrm, sz=dz/nrm;
    float xx=sx*sx, yy=sy*sy, zz=sz*sz, xyv=sx*sy, yzv=sy*sz, xzv=sx*sz;
    float sh[16];
    sh[0]=0.28209479177387814f;
    sh[1]=-0.48860251190291987f*sy;
    sh[2]= 0.48860251190291987f*sz;
    sh[3]=-0.48860251190291987f*sx;
    sh[4]= 1.0925484305920792f*xyv;
    sh[5]=-1.0925484305920792f*yzv;
    sh[6]= 0.94617469575756f*zz-0.31539156525252005f;
    sh[7]=-1.0925484305920792f*xzv;
    sh[8]= 0.5462742152960396f*(xx-yy);
    sh[9]=-0.5900435899266435f*sy*(3.f*xx-yy);
    sh[10]=2.890611442640554f*xyv*sz;
    sh[11]=-0.4570457994644658f*sy*(4.f*zz-xx-yy);
    sh[12]=0.3731763325901154f*sz*(2.f*zz-3.f*xx-3.f*yy);
    sh[13]=-0.4570457994644658f*sx*(4.f*zz-xx-yy);
    sh[14]=1.445305721320277f*sz*(xx-yy);
    sh[15]=-0.5900435899266435f*sx*(xx-3.f*yy);
#pragma unroll
    for (int k=0;k<16;k++){
        AXPY64(acc, &s_wc0T[k*64], sh[k]);
    }
#pragma unroll
    for (int j=0;j<15;j++){
        AXPY64(acc, &s_wc0T[(16+j)*64], h1[1+j]);
    }
    {
        int ai = (int)appf;
        const float* ar = embed_a + (size_t)ai*48;
        for (int q=0;q<12;q++){
            float4 av = ld4(ar + q*4);
            const float* wc = &s_wc0T[(31+q*4)*64];
            AXPY64(acc, wc,       av.x);
            AXPY64(acc, wc+64,    av.y);
            AXPY64(acc, wc+128,   av.z);
            AXPY64(acc, wc+192,   av.w);
        }
    }
#pragma unroll
    for (int j=0;j<24;j++){
        AXPY64(acc, &s_wc0T[(79+j)*64], pfv[j]);
    }

    float acc2[HID];
#pragma unroll
    for (int o=0;o<HID;o++) acc2[o]=0.f;
#pragma unroll
    for (int k=0;k<HID;k++){
        float v = fmaxf(acc[k], 0.f);
        AXPY64(acc2, &s_wc1T[k*64], v);
    }

    float c0a=0.f, c1a=0.f, c2a=0.f;
#pragma unroll
    for (int k=0;k<HID;k++){
        float v = fmaxf(acc2[k], 0.f);
        float4 w = ld4(&s_wc2T[k*4]);
        c0a=fmaf(w.x,v,c0a); c1a=fmaf(w.y,v,c1a); c2a=fmaf(w.z,v,c2a);
    }
    float4 o4;
    o4.x = 1.f/(1.f+expf(-c0a));
    o4.y = 1.f/(1.f+expf(-c1a));
    o4.z = 1.f/(1.f+expf(-c2a));
    o4.w = sigma;
    *reinterpret_cast<float4*>(out + (size_t)n*4) = o4;
}

extern "C" void kernel_launch(void* const* d_in, const int* in_sizes, int n_in,
                              void* d_out, int out_size, void* d_ws, size_t ws_size,
                              hipStream_t stream) {
    const float* x        = (const float*)d_in[0];
    const float* ht       = (const float*)d_in[1];
    const float* planes   = (const float*)d_in[2];
    const float* embed_a  = (const float*)d_in[3];
    const float* w_sigma0 = (const float*)d_in[4];
    const float* w_sigma1 = (const float*)d_in[5];
    const float* w_color0 = (const float*)d_in[6];
    const float* w_color1 = (const float*)d_in[7];
    const float* w_color2 = (const float*)d_in[8];
    float* out = (float*)d_out;

    int npts = in_sizes[0] / 7;

    ResArr res;
    double b = exp((log(2048.0) - log(16.0)) / 15.0);
    for (int l=0; l<NLEV; l++)
        res.v[l] = (float)floor(16.0 * pow(b, (double)l));

    // ws layout (bytes)
    const size_t OFF_S0  = 0;
    const size_t OFF_S1  = OFF_S0 + 56*64*4;
    const size_t OFF_C2  = OFF_S1 + 64*16*4;
    const size_t OFF_AP  = OFF_C2 + 64*4*4;
    const size_t OFF_B0H = OFF_AP + 1024*64*4;
    const size_t OFF_B0L = OFF_B0H + 4096*2;
    const size_t OFF_B1H = OFF_B0L + 4096*2;
    const size_t OFF_B1L = OFF_B1H + 4096*2;
    const size_t OFF_SB0H= OFF_B1L + 4096*2;
    const size_t OFF_SB0L= OFF_SB0H + 4096*2;
    const size_t OFF_SB1H= OFF_SB0L + 4096*2;
    const size_t OFF_SB1L= OFF_SB1H + 1024*2;
    const size_t OFF_C2BH= OFF_SB1L + 1024*2;
    const size_t OFF_C2BL= OFF_C2BH + 1024*2;
    const size_t OFF_SMALL_END = OFF_C2BL + 1024*2;
    size_t feat_bytes = (size_t)npts * 16 * sizeof(uint32_t);
    size_t pp_bytes   = (size_t)npts * 16;
    size_t tb_bytes   = (size_t)16 * TSIZE * 4;      // 32MB

    const size_t OFF_PP   = OFF_SMALL_END;
    const size_t OFF_TB   = OFF_PP + pp_bytes;
    const size_t OFF_FEAT2= OFF_TB + tb_bytes;
    const size_t OFF_FEAT1= OFF_SMALL_END;

    bool full_path = (ws_size >= OFF_FEAT2 + feat_bytes);
    bool mid_path  = (ws_size >= OFF_FEAT1 + feat_bytes);

    if (full_path || mid_path) {
        char* base = (char*)d_ws;
        float* t_s0  = (float*)(base + OFF_S0);
        float* t_s1  = (float*)(base + OFF_S1);
        float* t_c2  = (float*)(base + OFF_C2);
        float* a_pre = (float*)(base + OFF_AP);
        short* c0Bhi = (short*)(base + OFF_B0H);
        short* c0Blo = (short*)(base + OFF_B0L);
        short* c1Bhi = (short*)(base + OFF_B1H);
        short* c1Blo = (short*)(base + OFF_B1L);
        short* s0Bhi = (short*)(base + OFF_SB0H);
        short* s0Blo = (short*)(base + OFF_SB0L);
        short* s1Bhi = (short*)(base + OFF_SB1H);
        short* s1Blo = (short*)(base + OFF_SB1L);
        short* c2Bhi = (short*)(base + OFF_C2BH);
        short* c2Blo = (short*)(base + OFF_C2BL);

        // weight prep + app_pre in one launch (block0 = trans, blocks 1..1024 = app_pre)
        hipLaunchKernelGGL(nerf_ktrans, dim3(1025), dim3(256), 0, stream,
                           w_sigma0, w_sigma1, w_color0, w_color1, w_color2,
                           t_s0, t_s1, t_c2, c0Bhi, c0Blo, c1Bhi, c1Blo,
                           s0Bhi, s0Blo, s1Bhi, s1Blo, c2Bhi, c2Blo,
                           embed_a, a_pre);

        if (full_path) {
            float4*   pp      = (float4*)(base + OFF_PP);
            uint32_t* tabs_bf = (uint32_t*)(base + OFF_TB);
            uint32_t* feat    = (uint32_t*)(base + OFF_FEAT2);

            int total = 16 * (int)TSIZE;
            int nb_rep = (total + 255) / 256;
            int nb_pp  = (npts + 255) / 256;
            hipLaunchKernelGGL(nerf_krepack, dim3(nb_rep + nb_pp), dim3(256), 0, stream,
                               (const float2*)ht, tabs_bf, total, x, pp, npts);

            int chunks = (npts + 2047) / 2048;
            hipLaunchKernelGGL(nerf_k0b, dim3(8*chunks), dim3(256), 0, stream,
                               pp, tabs_bf, feat, res, npts, 0);
            hipLaunchKernelGGL(nerf_k0b, dim3(8*chunks), dim3(256), 0, stream,
                               pp, tabs_bf, feat, res, npts, 8);

            int gm = (npts + 63) / 64;
            hipLaunchKernelGGL(nerf_k12m, dim3(gm), dim3(64), 0, stream,
                               x, planes, feat, a_pre,
                               s0Bhi, s0Blo, s1Bhi, s1Blo,
                               c0Bhi, c0Blo, c1Bhi, c1Blo, c2Bhi, c2Blo, out, npts);
        } else {
            uint32_t* feat = (uint32_t*)(base + OFF_FEAT1);
            int chunks = (npts + 511) / 512;
            hipLaunchKernelGGL(nerf_k0, dim3(8*chunks), dim3(256), 0, stream,
                               x, ht, feat, res, npts, 0);
            hipLaunchKernelGGL(nerf_k0, dim3(8*chunks), dim3(256), 0, stream,
                               x, ht, feat, res, npts, 8);
            int g = (npts + 255) / 256;
            hipLaunchKernelGGL(nerf_k1s, dim3(g), dim3(256), 0, stream,
                               x, planes, feat, t_s0, t_s1, npts);
            int gm = (npts + 63) / 64;
            hipLaunchKernelGGL(nerf_k2m, dim3(gm), dim3(64), 0, stream,
                               x, planes, feat, a_pre,
                               c0Bhi, c0Blo, c1Bhi, c1Blo, t_c2, out, npts);
        }
    } else {
        int grid = (npts + 255) / 256;
        hipLaunchKernelGGL(nerf_fwd, dim3(grid), dim3(256), 0, stream,
                           x, ht, planes, embed_a,
                           w_sigma0, w_sigma1, w_color0, w_color1, w_color2,
                           out, res, npts);
    }
}